// Round 1
// baseline (595.210 us; speedup 1.0000x reference)
//
#include <hip/hip_runtime.h>
#include <math.h>

// ---- problem constants ----
#define B_   2
#define T_   2048
#define D_   1024
#define H_   16
#define DH_  64
#define DC_  1024
#define DFF_ 1656
#define DFFP_ 1664
#define MTOT 4096          // B_*T_
#define NELEM_X 4194304ull // B*T*D

typedef short s16x8 __attribute__((ext_vector_type(8)));
typedef unsigned short u16x4 __attribute__((ext_vector_type(4)));
typedef float f32x4 __attribute__((ext_vector_type(4)));
typedef unsigned short bfbits;

__device__ __forceinline__ bfbits f2bf(float f) {
  unsigned int u = __builtin_bit_cast(unsigned int, f);
  u += 0x7fffu + ((u >> 16) & 1u);          // RNE
  return (bfbits)(u >> 16);
}
__device__ __forceinline__ float bf2f(bfbits b) {
  unsigned int u = ((unsigned int)b) << 16;
  return __builtin_bit_cast(float, u);
}

__device__ __forceinline__ void gload16(const void* g, void* l) {
  __builtin_amdgcn_global_load_lds(
      (__attribute__((address_space(1))) void*)g,
      (__attribute__((address_space(3))) void*)l, 16, 0, 0);
}

// ---------- workspace offsets (bytes) ----------
constexpr size_t OFF_X1   = 0;                                  // f32 x1 ; later ff
constexpr size_t OFF_H    = OFF_X1 + 4ull*NELEM_X;              // bf16 h ; later h2
constexpr size_t OFF_Q    = OFF_H  + 2ull*NELEM_X;              // bf16 Q [BH][T][64] ; later ffmid
constexpr size_t OFF_K    = OFF_Q  + 2ull*NELEM_X;              // bf16 K [BH][T][64]
constexpr size_t OFF_VT   = OFF_K  + 2ull*NELEM_X;              // bf16 V^T [BH][64][T]
constexpr size_t OFF_AO   = OFF_VT + 2ull*NELEM_X;              // bf16 attn out [M][D]
constexpr size_t OFF_X2   = OFF_AO + 2ull*NELEM_X;              // f32 x2
constexpr size_t OFF_WQKV = OFF_X2 + 4ull*NELEM_X;              // bf16 [3072][1024]
constexpr size_t OFF_WO   = OFF_WQKV + 3072ull*1024*2;          // bf16 [1024][1024]
constexpr size_t OFF_WUP  = OFF_WO   + 1024ull*1024*2;          // bf16 [1664][1024]
constexpr size_t OFF_WDN  = OFF_WUP  + 1664ull*1024*2;          // bf16 [1024][1664]
constexpr size_t OFF_BVEC = OFF_WDN  + 1024ull*1664*2;          // f32 [B][D]
constexpr size_t OFF_CBV  = OFF_BVEC + 2048ull*4;               // f32 [B]
constexpr size_t OFF_GATE = OFF_CBV  + 256;                     // f32 [M]
constexpr size_t OFF_PART = OFF_GATE + 4096ull*4;               // f32 [32][1024]
constexpr size_t OFF_POOL = OFF_PART + 32ull*1024*4;            // f32 [B][D]
constexpr size_t OFF_CMT  = OFF_POOL + 2048ull*4;               // f32 [B]

// ---------- transpose f32 [R][C] -> bf16 [Npad][Rpad], dst[n][k] = (k<R && n<C) ? src[k][n] : 0
__global__ __launch_bounds__(256)
void transpose_w(const float* __restrict__ src, bfbits* __restrict__ dst,
                 int R, int C, int Rpad, int Npad) {
  __shared__ float tile[32][33];
  const int kb = blockIdx.x * 32, nb = blockIdx.y * 32;
  const int tx = threadIdx.x & 31, ty = threadIdx.x >> 5;
  for (int i = ty; i < 32; i += 8) {
    const int k = kb + i, n = nb + tx;
    tile[i][tx] = (k < R && n < C) ? src[(size_t)k * C + n] : 0.f;
  }
  __syncthreads();
  for (int i = ty; i < 32; i += 8) {
    const int n = nb + i, k = kb + tx;
    if (n < Npad && k < Rpad) dst[(size_t)n * Rpad + k] = f2bf(tile[tx][i]);
  }
}

// ---------- bvec[b][d] = center@bcast_w + bcast_b
__global__ __launch_bounds__(256)
void bvec_kernel(const float* __restrict__ cfa, const float* __restrict__ bw,
                 const float* __restrict__ bb, float* __restrict__ bvec) {
  const int idx = blockIdx.x * 256 + threadIdx.x; // 0..2047
  const int b = idx >> 10, d = idx & 1023;
  const float* a = cfa + b * 1024;
  float s = 0.f;
  for (int c = 0; c < 1024; ++c) s += a[c] * bw[(size_t)c * 1024 + d];
  bvec[idx] = s + bb[d];
}

__global__ __launch_bounds__(256)
void cb_kernel(const float* __restrict__ cfa, const float* __restrict__ cbw,
               float* __restrict__ cbv) {
  const int b = blockIdx.x, tid = threadIdx.x;
  float4 a = *(const float4*)(cfa + b * 1024 + tid * 4);
  float4 w = *(const float4*)(cbw + tid * 4);
  float s = a.x * w.x + a.y * w.y + a.z * w.z + a.w * w.w;
  #pragma unroll
  for (int o = 32; o > 0; o >>= 1) s += __shfl_xor(s, o);
  __shared__ float ls[4];
  if ((tid & 63) == 0) ls[tid >> 6] = s;
  __syncthreads();
  if (tid == 0) cbv[b] = ls[0] + ls[1] + ls[2] + ls[3];
}

__device__ __forceinline__ void blockreduce3(float& a, float& b, float& c) {
  #pragma unroll
  for (int o = 32; o > 0; o >>= 1) {
    a += __shfl_xor(a, o);
    b += __shfl_xor(b, o);
    c += __shfl_xor(c, o);
  }
  __shared__ float ls[3][4];
  const int lane = threadIdx.x & 63, w = threadIdx.x >> 6;
  if (lane == 0) { ls[0][w] = a; ls[1][w] = b; ls[2][w] = c; }
  __syncthreads();
  a = ls[0][0] + ls[0][1] + ls[0][2] + ls[0][3];
  b = ls[1][0] + ls[1][1] + ls[1][2] + ls[1][3];
  c = ls[2][0] + ls[2][1] + ls[2][2] + ls[2][3];
}

// ---------- fused: x1 = x + bvec ; gate ; LN(x1) -> h (bf16)
__global__ __launch_bounds__(256)
void ln1_kernel(const float* __restrict__ x, const float* __restrict__ bvec,
                const float* __restrict__ cbv, const float* __restrict__ gw,
                const float* __restrict__ gb, const float* __restrict__ nfg,
                const float* __restrict__ nfb, float* __restrict__ x1,
                bfbits* __restrict__ h, float* __restrict__ gate_ws,
                float* __restrict__ gate_out) {
  const int m = blockIdx.x, tid = threadIdx.x, b = m >> 11;
  const size_t ro = (size_t)m * D_ + tid * 4;
  float4 xv = *(const float4*)(x + ro);
  float4 bv = *(const float4*)(bvec + b * D_ + tid * 4);
  float4 v;
  v.x = xv.x + bv.x; v.y = xv.y + bv.y; v.z = xv.z + bv.z; v.w = xv.w + bv.w;
  float4 g4 = *(const float4*)(gw + tid * 4);
  float s  = v.x + v.y + v.z + v.w;
  float s2 = v.x*v.x + v.y*v.y + v.z*v.z + v.w*v.w;
  float dg = v.x*g4.x + v.y*g4.y + v.z*g4.z + v.w*g4.w;
  blockreduce3(s, s2, dg);
  const float mean = s * (1.0f/1024.0f);
  const float var  = s2 * (1.0f/1024.0f) - mean*mean;
  const float rstd = rsqrtf(var + 1e-5f);
  if (tid == 0) {
    const float logits = dg + gb[0] + cbv[b];
    const float prob = 1.0f / (1.0f + expf(-logits));
    const float hard = prob > 0.5f ? 1.0f : 0.0f;
    const float gv = (hard - prob) + prob;
    gate_ws[m] = gv; gate_out[m] = gv;
  }
  *(float4*)(x1 + ro) = v;
  float4 gg = *(const float4*)(nfg + tid * 4);
  float4 b2 = *(const float4*)(nfb + tid * 4);
  u16x4 hv;
  hv[0] = f2bf((v.x - mean) * rstd * gg.x + b2.x);
  hv[1] = f2bf((v.y - mean) * rstd * gg.y + b2.y);
  hv[2] = f2bf((v.z - mean) * rstd * gg.z + b2.z);
  hv[3] = f2bf((v.w - mean) * rstd * gg.w + b2.w);
  *(u16x4*)(h + ro) = hv;
}

__global__ __launch_bounds__(256)
void ln2_kernel(const float* __restrict__ x2, const float* __restrict__ gptr,
                const float* __restrict__ bptr, bfbits* __restrict__ h2) {
  const int m = blockIdx.x, tid = threadIdx.x;
  const size_t ro = (size_t)m * D_ + tid * 4;
  float4 v = *(const float4*)(x2 + ro);
  float s  = v.x + v.y + v.z + v.w;
  float s2 = v.x*v.x + v.y*v.y + v.z*v.z + v.w*v.w;
  float d0 = 0.f;
  blockreduce3(s, s2, d0);
  const float mean = s * (1.0f/1024.0f);
  const float var  = s2 * (1.0f/1024.0f) - mean*mean;
  const float rstd = rsqrtf(var + 1e-5f);
  float4 gg = *(const float4*)(gptr + tid * 4);
  float4 b2 = *(const float4*)(bptr + tid * 4);
  u16x4 hv;
  hv[0] = f2bf((v.x - mean) * rstd * gg.x + b2.x);
  hv[1] = f2bf((v.y - mean) * rstd * gg.y + b2.y);
  hv[2] = f2bf((v.z - mean) * rstd * gg.z + b2.z);
  hv[3] = f2bf((v.w - mean) * rstd * gg.w + b2.w);
  *(u16x4*)(h2 + ro) = hv;
}

// ---------- GEMM: C[M][N] = A[M][K](bf16,row-major) * Bt[N][K](bf16) with fused epilogues
// EPI 0: QKV (rope+gate, Q scaled 1/8; V -> V^T)   EPI 1: WO (x2 = x1 + C*gate)
// EPI 2: UP (gelu(C+up_b) -> bf16, ldc=1664)       EPI 3: DN (C+dn_b -> f32)
template <int EPI>
__global__ void __launch_bounds__(256, 2)
gemm_bt(const bfbits* __restrict__ A, int lda,
        const bfbits* __restrict__ Bt, int ldb, int K,
        const float* __restrict__ p0, const float* __restrict__ p1,
        float* __restrict__ fo0, bfbits* __restrict__ bo0,
        bfbits* __restrict__ bo1, bfbits* __restrict__ bo2) {
  __shared__ bfbits Asl[128 * 32];
  __shared__ bfbits Bsl[128 * 32];
  const int tid = threadIdx.x;
  const int lane = tid & 63, wave = tid >> 6;
  const int g = lane >> 4, l15 = lane & 15;
  const int wr = wave >> 1, wc = wave & 1;
  const int m0 = blockIdx.y * 128, n0 = blockIdx.x * 128;

  f32x4 acc[4][4] = {};

  for (int k0 = 0; k0 < K; k0 += 32) {
    #pragma unroll
    for (int p = 0; p < 2; ++p) {
      const int chunk = wave + p * 4;            // 0..7
      const int e = chunk * 512 + lane * 8;      // element in 128x32 tile
      const int row = e >> 5, ko = e & 31;
      gload16(A  + (size_t)(m0 + row) * lda + (k0 + ko), (char*)Asl + chunk * 1024);
      gload16(Bt + (size_t)(n0 + row) * ldb + (k0 + ko), (char*)Bsl + chunk * 1024);
    }
    __syncthreads();
    s16x8 af[4], bfr[4];
    #pragma unroll
    for (int i = 0; i < 4; ++i) af[i]  = *(const s16x8*)&Asl[(wr * 64 + i * 16 + l15) * 32 + g * 8];
    #pragma unroll
    for (int i = 0; i < 4; ++i) bfr[i] = *(const s16x8*)&Bsl[(wc * 64 + i * 16 + l15) * 32 + g * 8];
    #pragma unroll
    for (int i = 0; i < 4; ++i)
      #pragma unroll
      for (int j = 0; j < 4; ++j)
        acc[i][j] = __builtin_amdgcn_mfma_f32_16x16x32_bf16(af[i], bfr[j], acc[i][j], 0, 0, 0);
    __syncthreads();
  }

  const int b = m0 >> 11;
  const int trow0 = (m0 & 2047) + wr * 64;

  if constexpr (EPI == 0) {
    const float* gate = p0;
    const float* phase = p1;
    const int ncol0 = n0 + wc * 64;           // 64-aligned wave column base
    const int section = ncol0 >> 10;          // 0=Q 1=K 2=V
    const int hh = (ncol0 & 1023) >> 6;
    if (section == 2) {
      bfbits* vt = bo2;
      const size_t vhead = (size_t)(b * H_ + hh) * DH_ * T_;
      #pragma unroll
      for (int mi = 0; mi < 4; ++mi) {
        const int tb = trow0 + mi * 16 + g * 4;
        #pragma unroll
        for (int ni = 0; ni < 4; ++ni) {
          const int dh = ni * 16 + l15;
          #pragma unroll
          for (int r = 0; r < 4; ++r)
            vt[vhead + (size_t)dh * T_ + (tb + r)] = f2bf(acc[mi][ni][r]);
        }
      }
    } else {
      const float cc = cosf(phase[hh]);
      const float ssn = sinf(phase[hh]);
      const float qs = (section == 0) ? 0.125f : 1.0f;
      bfbits* dst = (section == 0) ? bo0 : bo1;
      const size_t head = (size_t)(b * H_ + hh) * T_ * DH_;
      #pragma unroll
      for (int mi = 0; mi < 4; ++mi) {
        const int tb = trow0 + mi * 16 + g * 4;
        float gv[4];
        #pragma unroll
        for (int r = 0; r < 4; ++r) gv[r] = gate[(size_t)b * T_ + tb + r] * qs;
        #pragma unroll
        for (int ni = 0; ni < 2; ++ni) {
          const int dh = ni * 16 + l15;
          #pragma unroll
          for (int r = 0; r < 4; ++r) {
            const float re = acc[mi][ni][r];
            const float im = acc[mi][ni + 2][r];
            const size_t idx = head + (size_t)(tb + r) * DH_ + dh;
            dst[idx]      = f2bf((re * cc - im * ssn) * gv[r]);
            dst[idx + 32] = f2bf((re * ssn + im * cc) * gv[r]);
          }
        }
      }
    }
  } else if constexpr (EPI == 1) {
    const float* gate = p0;
    const float* x1 = p1;
    float* x2 = fo0;
    #pragma unroll
    for (int mi = 0; mi < 4; ++mi) {
      const int m = m0 + wr * 64 + mi * 16 + g * 4;
      float gv[4];
      #pragma unroll
      for (int r = 0; r < 4; ++r) gv[r] = gate[m + r];
      #pragma unroll
      for (int ni = 0; ni < 4; ++ni) {
        const int n = n0 + wc * 64 + ni * 16 + l15;
        #pragma unroll
        for (int r = 0; r < 4; ++r) {
          const size_t idx = (size_t)(m + r) * D_ + n;
          x2[idx] = x1[idx] + acc[mi][ni][r] * gv[r];
        }
      }
    }
  } else if constexpr (EPI == 2) {
    const float* upb = p0;
    bfbits* outm = bo0;
    #pragma unroll
    for (int mi = 0; mi < 4; ++mi) {
      const int m = m0 + wr * 64 + mi * 16 + g * 4;
      #pragma unroll
      for (int ni = 0; ni < 4; ++ni) {
        const int n = n0 + wc * 64 + ni * 16 + l15;
        const float bb = upb[n];
        #pragma unroll
        for (int r = 0; r < 4; ++r) {
          float v = acc[mi][ni][r] + bb;
          v = 0.5f * v * (1.0f + erff(v * 0.70710678118654752f));
          outm[(size_t)(m + r) * DFFP_ + n] = f2bf(v);
        }
      }
    }
  } else {
    const float* dnb = p0;
    float* outf = fo0;
    #pragma unroll
    for (int mi = 0; mi < 4; ++mi) {
      const int m = m0 + wr * 64 + mi * 16 + g * 4;
      #pragma unroll
      for (int ni = 0; ni < 4; ++ni) {
        const int n = n0 + wc * 64 + ni * 16 + l15;
        const float bb = dnb[n];
        #pragma unroll
        for (int r = 0; r < 4; ++r)
          outf[(size_t)(m + r) * D_ + n] = acc[mi][ni][r] + bb;
      }
    }
  }
}

// ---------- flash attention: 1 wave per (bh, 16 q-rows); swapped QK^T + O^T PV
__global__ void __launch_bounds__(64)
attn_kernel(const bfbits* __restrict__ Qb, const bfbits* __restrict__ Kb,
            const bfbits* __restrict__ Vt, bfbits* __restrict__ AO) {
  const int qt = blockIdx.x;   // 0..127
  const int bh = blockIdx.y;   // 0..31
  const int lane = threadIdx.x;
  const int g = lane >> 4, l15 = lane & 15;
  const int qbase = qt * 16;

  const bfbits* Qp = Qb + ((size_t)bh * T_ + qbase) * DH_;
  const bfbits* Kp = Kb + (size_t)bh * T_ * DH_;
  const bfbits* Vp = Vt + (size_t)bh * DH_ * T_;

  const s16x8 q0 = *(const s16x8*)(Qp + l15 * DH_ + g * 8);
  const s16x8 q1 = *(const s16x8*)(Qp + l15 * DH_ + 32 + g * 8);

  f32x4 o[4] = {};
  float mrun = -INFINITY, lrun = 0.f;

  const int kend = qbase + 16;
  for (int k0 = 0; k0 < kend; k0 += 32) {
    const bfbits* K0 = Kp + (size_t)(k0 + l15) * DH_;
    f32x4 st0 = {0.f, 0.f, 0.f, 0.f}, st1 = {0.f, 0.f, 0.f, 0.f};
    {
      s16x8 ka  = *(const s16x8*)(K0 + g * 8);
      s16x8 kb2 = *(const s16x8*)(K0 + 32 + g * 8);
      st0 = __builtin_amdgcn_mfma_f32_16x16x32_bf16(ka,  q0, st0, 0, 0, 0);
      st0 = __builtin_amdgcn_mfma_f32_16x16x32_bf16(kb2, q1, st0, 0, 0, 0);
      const bfbits* K1 = K0 + 16 * DH_;
      ka  = *(const s16x8*)(K1 + g * 8);
      kb2 = *(const s16x8*)(K1 + 32 + g * 8);
      st1 = __builtin_amdgcn_mfma_f32_16x16x32_bf16(ka,  q0, st1, 0, 0, 0);
      st1 = __builtin_amdgcn_mfma_f32_16x16x32_bf16(kb2, q1, st1, 0, 0, 0);
    }
    if (k0 + 31 > qbase) {              // diagonal tiles: causal mask
      const int q = qbase + l15;
      #pragma unroll
      for (int r = 0; r < 4; ++r) {
        if (k0 + g * 4 + r > q)      st0[r] = -1e9f;
        if (k0 + 16 + g * 4 + r > q) st1[r] = -1e9f;
      }
    }
    float mx = fmaxf(fmaxf(fmaxf(st0[0], st0[1]), fmaxf(st0[2], st0[3])),
                     fmaxf(fmaxf(st1[0], st1[1]), fmaxf(st1[2], st1[3])));
    mx = fmaxf(mx, __shfl_xor(mx, 16));
    mx = fmaxf(mx, __shfl_xor(mx, 32));
    const float mnew = fmaxf(mrun, mx);
    float p[8];
    #pragma unroll
    for (int r = 0; r < 4; ++r) {
      p[r]     = __expf(st0[r] - mnew);
      p[4 + r] = __expf(st1[r] - mnew);
    }
    float sum = p[0] + p[1] + p[2] + p[3] + p[4] + p[5] + p[6] + p[7];
    sum += __shfl_xor(sum, 16);
    sum += __shfl_xor(sum, 32);
    const float alpha = __expf(mrun - mnew);
    lrun = lrun * alpha + sum;
    mrun = mnew;
    s16x8 pf;
    #pragma unroll
    for (int j = 0; j < 8; ++j) pf[j] = (short)f2bf(p[j]);
    #pragma unroll
    for (int dt = 0; dt < 4; ++dt) {
      o[dt][0] *= alpha; o[dt][1] *= alpha; o[dt][2] *= alpha; o[dt][3] *= alpha;
      const bfbits* Vrow = Vp + (size_t)(dt * 16 + l15) * T_ + k0;
      u16x4 vlo = *(const u16x4*)(Vrow + g * 4);
      u16x4 vhi = *(const u16x4*)(Vrow + 16 + g * 4);
      s16x8 vf;
      vf[0] = (short)vlo[0]; vf[1] = (short)vlo[1]; vf[2] = (short)vlo[2]; vf[3] = (short)vlo[3];
      vf[4] = (short)vhi[0]; vf[5] = (short)vhi[1]; vf[6] = (short)vhi[2]; vf[7] = (short)vhi[3];
      o[dt] = __builtin_amdgcn_mfma_f32_16x16x32_bf16(vf, pf, o[dt], 0, 0, 0);
    }
  }
  const float inv = 1.0f / lrun;
  const int b = bh >> 4, hh = bh & 15;
  bfbits* dst = AO + ((size_t)b * T_ + qbase + l15) * D_ + hh * DH_;
  #pragma unroll
  for (int dt = 0; dt < 4; ++dt)
    #pragma unroll
    for (int r = 0; r < 4; ++r)
      dst[dt * 16 + g * 4 + r] = f2bf(o[dt][r] * inv);
}

// ---------- pooling / commit / center / final ----------
__global__ __launch_bounds__(256)
void pool_part(const float* __restrict__ x2, float* __restrict__ part) {
  const int s = blockIdx.x, b = blockIdx.y, tid = threadIdx.x;
  const float* base = x2 + ((size_t)b * T_ + s * 128) * D_ + tid * 4;
  float ax = 0, ay = 0, az = 0, aw = 0;
  for (int t = 0; t < 128; ++t) {
    float4 v = *(const float4*)(base + (size_t)t * D_);
    ax += v.x; ay += v.y; az += v.z; aw += v.w;
  }
  float4 ov; ov.x = ax; ov.y = ay; ov.z = az; ov.w = aw;
  *(float4*)(part + (size_t)(b * 16 + s) * D_ + tid * 4) = ov;
}

__global__ __launch_bounds__(256)
void pool_fin(const float* __restrict__ part, float* __restrict__ pool) {
  const int idx = blockIdx.x * 256 + threadIdx.x; // 0..2047
  const int b = idx >> 10, d = idx & 1023;
  float s = 0.f;
  for (int i = 0; i < 16; ++i) s += part[(size_t)(b * 16 + i) * D_ + d];
  pool[idx] = s * (1.0f / 2048.0f);
}

__global__ __launch_bounds__(256)
void commit_kernel(const float* __restrict__ pool, const float* __restrict__ cw,
                   const float* __restrict__ cb0, float* __restrict__ cmt,
                   float* __restrict__ out_cmt) {
  const int b = blockIdx.x, tid = threadIdx.x;
  float4 p = *(const float4*)(pool + b * 1024 + tid * 4);
  float4 w = *(const float4*)(cw + tid * 4);
  float s = p.x * w.x + p.y * w.y + p.z * w.z + p.w * w.w;
  #pragma unroll
  for (int o = 32; o > 0; o >>= 1) s += __shfl_xor(s, o);
  __shared__ float ls[4];
  if ((tid & 63) == 0) ls[tid >> 6] = s;
  __syncthreads();
  if (tid == 0) {
    const float t = ls[0] + ls[1] + ls[2] + ls[3] + cb0[0];
    const float v = 1.0f / (1.0f + expf(-t));
    cmt[b] = v; out_cmt[b] = v;
  }
}

__global__ __launch_bounds__(256)
void center_kernel(const float* __restrict__ pool, const float* __restrict__ cpw,
                   const float* __restrict__ cpb, float* __restrict__ outc) {
  const int idx = blockIdx.x * 256 + threadIdx.x; // 0..2047
  const int b = idx >> 10, c = idx & 1023;
  const float* pb = pool + b * 1024;
  float s = 0.f;
  for (int d = 0; d < 1024; ++d) s += pb[d] * cpw[(size_t)d * 1024 + c];
  outc[idx] = tanhf(s + cpb[c]);
}

__global__ __launch_bounds__(256)
void final_kernel(const float* __restrict__ x2, const float* __restrict__ ff,
                  const float* __restrict__ gate, const float* __restrict__ cmt,
                  float* __restrict__ outx) {
  const size_t i = (size_t)blockIdx.x * 256 + threadIdx.x; // * 4 elements
  const int m = (int)(i >> 8);
  const int b = m >> 11;
  const float k = cmt[b] * gate[m];
  float4 xv = *(const float4*)(x2 + i * 4);
  float4 fv = *(const float4*)(ff + i * 4);
  float4 ov;
  ov.x = xv.x + k * fv.x; ov.y = xv.y + k * fv.y;
  ov.z = xv.z + k * fv.z; ov.w = xv.w + k * fv.w;
  *(float4*)(outx + i * 4) = ov;
}

// ---------------- host launcher ----------------
extern "C" void kernel_launch(void* const* d_in, const int* in_sizes, int n_in,
                              void* d_out, int out_size, void* d_ws, size_t ws_size,
                              hipStream_t stream) {
  (void)in_sizes; (void)n_in; (void)out_size; (void)ws_size;
  const float* x       = (const float*)d_in[0];
  const float* cfa     = (const float*)d_in[1];
  const float* gate_w  = (const float*)d_in[3];
  const float* gate_b  = (const float*)d_in[4];
  const float* cb_w    = (const float*)d_in[5];
  const float* nf_g    = (const float*)d_in[6];
  const float* nf_b    = (const float*)d_in[7];
  const float* wq      = (const float*)d_in[8];
  const float* wk      = (const float*)d_in[9];
  const float* wv      = (const float*)d_in[10];
  const float* wo      = (const float*)d_in[11];
  const float* phase   = (const float*)d_in[12];
  const float* nb_g    = (const float*)d_in[13];
  const float* nb_b    = (const float*)d_in[14];
  const float* up_w    = (const float*)d_in[15];
  const float* up_b    = (const float*)d_in[16];
  const float* dn_w    = (const float*)d_in[17];
  const float* dn_b    = (const float*)d_in[18];
  const float* cmt_w   = (const float*)d_in[19];
  const float* cmt_b   = (const float*)d_in[20];
  const float* cproj_w = (const float*)d_in[21];
  const float* cproj_b = (const float*)d_in[22];
  const float* bcast_w = (const float*)d_in[23];
  const float* bcast_b = (const float*)d_in[24];

  char* ws = (char*)d_ws;
  float*  x1     = (float*)(ws + OFF_X1);
  float*  ff     = (float*)(ws + OFF_X1);     // alias: x1 dead after WO
  bfbits* h      = (bfbits*)(ws + OFF_H);
  bfbits* h2     = (bfbits*)(ws + OFF_H);     // alias: h dead after QKV
  bfbits* qb     = (bfbits*)(ws + OFF_Q);
  bfbits* kb     = (bfbits*)(ws + OFF_K);
  bfbits* vt     = (bfbits*)(ws + OFF_VT);
  bfbits* ffmid  = (bfbits*)(ws + OFF_Q);     // alias: Q/K dead after attention
  bfbits* ao     = (bfbits*)(ws + OFF_AO);
  float*  x2     = (float*)(ws + OFF_X2);
  bfbits* wqkv_t = (bfbits*)(ws + OFF_WQKV);
  bfbits* wo_t   = (bfbits*)(ws + OFF_WO);
  bfbits* wup_t  = (bfbits*)(ws + OFF_WUP);
  bfbits* wdn_t  = (bfbits*)(ws + OFF_WDN);
  float*  bvec   = (float*)(ws + OFF_BVEC);
  float*  cbv    = (float*)(ws + OFF_CBV);
  float*  gate   = (float*)(ws + OFF_GATE);
  float*  part   = (float*)(ws + OFF_PART);
  float*  pool   = (float*)(ws + OFF_POOL);
  float*  cmt    = (float*)(ws + OFF_CMT);

  float* outx   = (float*)d_out;
  float* outc   = outx + NELEM_X;          // center [B][DC]
  float* outg   = outc + B_ * DC_;         // gate [B][T]
  float* outcmt = outg + B_ * T_;          // commit [B]

  // weight prep (B^T bf16)
  transpose_w<<<dim3(32, 32), 256, 0, stream>>>(wq, wqkv_t,                1024, 1024, 1024, 1024);
  transpose_w<<<dim3(32, 32), 256, 0, stream>>>(wk, wqkv_t + 1024 * 1024,  1024, 1024, 1024, 1024);
  transpose_w<<<dim3(32, 32), 256, 0, stream>>>(wv, wqkv_t + 2048 * 1024,  1024, 1024, 1024, 1024);
  transpose_w<<<dim3(32, 32), 256, 0, stream>>>(wo, wo_t,                  1024, 1024, 1024, 1024);
  transpose_w<<<dim3(32, 52), 256, 0, stream>>>(up_w, wup_t,               1024, DFF_, 1024, DFFP_);
  transpose_w<<<dim3(52, 32), 256, 0, stream>>>(dn_w, wdn_t,               DFF_, 1024, DFFP_, 1024);

  bvec_kernel<<<8, 256, 0, stream>>>(cfa, bcast_w, bcast_b, bvec);
  cb_kernel<<<B_, 256, 0, stream>>>(cfa, cb_w, cbv);

  ln1_kernel<<<MTOT, 256, 0, stream>>>(x, bvec, cbv, gate_w, gate_b, nf_g, nf_b,
                                       x1, h, gate, outg);

  gemm_bt<0><<<dim3(24, 32), 256, 0, stream>>>(h, 1024, wqkv_t, 1024, 1024,
                                               gate, phase, nullptr, qb, kb, vt);

  attn_kernel<<<dim3(128, 32), 64, 0, stream>>>(qb, kb, vt, ao);

  gemm_bt<1><<<dim3(8, 32), 256, 0, stream>>>(ao, 1024, wo_t, 1024, 1024,
                                              gate, x1, x2, nullptr, nullptr, nullptr);

  ln2_kernel<<<MTOT, 256, 0, stream>>>(x2, nb_g, nb_b, h2);

  gemm_bt<2><<<dim3(13, 32), 256, 0, stream>>>(h2, 1024, wup_t, 1024, 1024,
                                               up_b, nullptr, nullptr, ffmid, nullptr, nullptr);

  gemm_bt<3><<<dim3(8, 32), 256, 0, stream>>>(ffmid, DFFP_, wdn_t, DFFP_, DFFP_,
                                              dn_b, nullptr, ff, nullptr, nullptr, nullptr);

  pool_part<<<dim3(16, B_), 256, 0, stream>>>(x2, part);
  pool_fin<<<8, 256, 0, stream>>>(part, pool);
  commit_kernel<<<B_, 256, 0, stream>>>(pool, cmt_w, cmt_b, cmt, outcmt);
  center_kernel<<<8, 256, 0, stream>>>(pool, cproj_w, cproj_b, outc);

  final_kernel<<<4096, 256, 0, stream>>>(x2, ff, gate, cmt, outx);
}

// Round 2
// 334.653 us; speedup vs baseline: 1.7786x; 1.7786x over previous
//
#include <hip/hip_runtime.h>
#include <math.h>

// ---- problem constants ----
#define B_   2
#define T_   2048
#define D_   1024
#define H_   16
#define DH_  64
#define DC_  1024
#define DFF_ 1656
#define DFFP_ 1664
#define MTOT 4096          // B_*T_
#define NELEM_X 4194304ull // B*T*D

typedef short s16x8 __attribute__((ext_vector_type(8)));
typedef unsigned short u16x4 __attribute__((ext_vector_type(4)));
typedef float f32x4 __attribute__((ext_vector_type(4)));
typedef unsigned short bfbits;

__device__ __forceinline__ bfbits f2bf(float f) {
  unsigned int u = __builtin_bit_cast(unsigned int, f);
  u += 0x7fffu + ((u >> 16) & 1u);          // RNE
  return (bfbits)(u >> 16);
}
__device__ __forceinline__ float bf2f(bfbits b) {
  unsigned int u = ((unsigned int)b) << 16;
  return __builtin_bit_cast(float, u);
}

__device__ __forceinline__ void gload16(const void* g, void* l) {
  __builtin_amdgcn_global_load_lds(
      (__attribute__((address_space(1))) void*)g,
      (__attribute__((address_space(3))) void*)l, 16, 0, 0);
}

// ---------- workspace offsets (bytes) ----------
constexpr size_t OFF_X1   = 0;                                  // f32 x1 ; later ff
constexpr size_t OFF_H    = OFF_X1 + 4ull*NELEM_X;              // bf16 h ; later h2
constexpr size_t OFF_Q    = OFF_H  + 2ull*NELEM_X;              // bf16 Q [BH][T][64] ; later ffmid
constexpr size_t OFF_K    = OFF_Q  + 2ull*NELEM_X;              // bf16 K [BH][T][64]
constexpr size_t OFF_VT   = OFF_K  + 2ull*NELEM_X;              // bf16 V^T [BH][64][T]
constexpr size_t OFF_AO   = OFF_VT + 2ull*NELEM_X;              // bf16 attn out [M][D]
constexpr size_t OFF_X2   = OFF_AO + 2ull*NELEM_X;              // f32 x2
constexpr size_t OFF_WQKV = OFF_X2 + 4ull*NELEM_X;              // bf16 [3072][1024]
constexpr size_t OFF_WO   = OFF_WQKV + 3072ull*1024*2;          // bf16 [1024][1024]
constexpr size_t OFF_WUP  = OFF_WO   + 1024ull*1024*2;          // bf16 [1664][1024]
constexpr size_t OFF_WDN  = OFF_WUP  + 1664ull*1024*2;          // bf16 [1024][1664]
constexpr size_t OFF_BVEC = OFF_WDN  + 1024ull*1664*2;          // f32 [B][D]
constexpr size_t OFF_CBV  = OFF_BVEC + 2048ull*4;               // f32 [B]
constexpr size_t OFF_GATE = OFF_CBV  + 256;                     // f32 [M]
constexpr size_t OFF_PART = OFF_GATE + 4096ull*4;               // f32 [32][1024]
constexpr size_t OFF_POOL = OFF_PART + 32ull*1024*4;            // f32 [B][D]
constexpr size_t OFF_CMT  = OFF_POOL + 2048ull*4;               // f32 [B]

// ---------- transpose f32 [R][C] -> bf16 [Npad][Rpad], dst[n][k] = (k<R && n<C) ? src[k][n] : 0
__global__ __launch_bounds__(256)
void transpose_w(const float* __restrict__ src, bfbits* __restrict__ dst,
                 int R, int C, int Rpad, int Npad) {
  __shared__ float tile[32][33];
  const int kb = blockIdx.x * 32, nb = blockIdx.y * 32;
  const int tx = threadIdx.x & 31, ty = threadIdx.x >> 5;
  for (int i = ty; i < 32; i += 8) {
    const int k = kb + i, n = nb + tx;
    tile[i][tx] = (k < R && n < C) ? src[(size_t)k * C + n] : 0.f;
  }
  __syncthreads();
  for (int i = ty; i < 32; i += 8) {
    const int n = nb + i, k = kb + tx;
    if (n < Npad && k < Rpad) dst[(size_t)n * Rpad + k] = f2bf(tile[tx][i]);
  }
}

// ---------- bvec[b][d] = center@bcast_w + bcast_b
__global__ __launch_bounds__(256)
void bvec_kernel(const float* __restrict__ cfa, const float* __restrict__ bw,
                 const float* __restrict__ bb, float* __restrict__ bvec) {
  const int idx = blockIdx.x * 256 + threadIdx.x; // 0..2047
  const int b = idx >> 10, d = idx & 1023;
  const float* a = cfa + b * 1024;
  float s = 0.f;
  for (int c = 0; c < 1024; ++c) s += a[c] * bw[(size_t)c * 1024 + d];
  bvec[idx] = s + bb[d];
}

__global__ __launch_bounds__(256)
void cb_kernel(const float* __restrict__ cfa, const float* __restrict__ cbw,
               float* __restrict__ cbv) {
  const int b = blockIdx.x, tid = threadIdx.x;
  float4 a = *(const float4*)(cfa + b * 1024 + tid * 4);
  float4 w = *(const float4*)(cbw + tid * 4);
  float s = a.x * w.x + a.y * w.y + a.z * w.z + a.w * w.w;
  #pragma unroll
  for (int o = 32; o > 0; o >>= 1) s += __shfl_xor(s, o);
  __shared__ float ls[4];
  if ((tid & 63) == 0) ls[tid >> 6] = s;
  __syncthreads();
  if (tid == 0) cbv[b] = ls[0] + ls[1] + ls[2] + ls[3];
}

__device__ __forceinline__ void blockreduce3(float& a, float& b, float& c) {
  #pragma unroll
  for (int o = 32; o > 0; o >>= 1) {
    a += __shfl_xor(a, o);
    b += __shfl_xor(b, o);
    c += __shfl_xor(c, o);
  }
  __shared__ float ls[3][4];
  const int lane = threadIdx.x & 63, w = threadIdx.x >> 6;
  if (lane == 0) { ls[0][w] = a; ls[1][w] = b; ls[2][w] = c; }
  __syncthreads();
  a = ls[0][0] + ls[0][1] + ls[0][2] + ls[0][3];
  b = ls[1][0] + ls[1][1] + ls[1][2] + ls[1][3];
  c = ls[2][0] + ls[2][1] + ls[2][2] + ls[2][3];
}

// ---------- fused: x1 = x + bvec ; gate ; LN(x1) -> h (bf16)
__global__ __launch_bounds__(256)
void ln1_kernel(const float* __restrict__ x, const float* __restrict__ bvec,
                const float* __restrict__ cbv, const float* __restrict__ gw,
                const float* __restrict__ gb, const float* __restrict__ nfg,
                const float* __restrict__ nfb, float* __restrict__ x1,
                bfbits* __restrict__ h, float* __restrict__ gate_ws,
                float* __restrict__ gate_out) {
  const int m = blockIdx.x, tid = threadIdx.x, b = m >> 11;
  const size_t ro = (size_t)m * D_ + tid * 4;
  float4 xv = *(const float4*)(x + ro);
  float4 bv = *(const float4*)(bvec + b * D_ + tid * 4);
  float4 v;
  v.x = xv.x + bv.x; v.y = xv.y + bv.y; v.z = xv.z + bv.z; v.w = xv.w + bv.w;
  float4 g4 = *(const float4*)(gw + tid * 4);
  float s  = v.x + v.y + v.z + v.w;
  float s2 = v.x*v.x + v.y*v.y + v.z*v.z + v.w*v.w;
  float dg = v.x*g4.x + v.y*g4.y + v.z*g4.z + v.w*g4.w;
  blockreduce3(s, s2, dg);
  const float mean = s * (1.0f/1024.0f);
  const float var  = s2 * (1.0f/1024.0f) - mean*mean;
  const float rstd = rsqrtf(var + 1e-5f);
  if (tid == 0) {
    const float logits = dg + gb[0] + cbv[b];
    const float prob = 1.0f / (1.0f + expf(-logits));
    const float hard = prob > 0.5f ? 1.0f : 0.0f;
    const float gv = (hard - prob) + prob;
    gate_ws[m] = gv; gate_out[m] = gv;
  }
  *(float4*)(x1 + ro) = v;
  float4 gg = *(const float4*)(nfg + tid * 4);
  float4 b2 = *(const float4*)(nfb + tid * 4);
  u16x4 hv;
  hv[0] = f2bf((v.x - mean) * rstd * gg.x + b2.x);
  hv[1] = f2bf((v.y - mean) * rstd * gg.y + b2.y);
  hv[2] = f2bf((v.z - mean) * rstd * gg.z + b2.z);
  hv[3] = f2bf((v.w - mean) * rstd * gg.w + b2.w);
  *(u16x4*)(h + ro) = hv;
}

__global__ __launch_bounds__(256)
void ln2_kernel(const float* __restrict__ x2, const float* __restrict__ gptr,
                const float* __restrict__ bptr, bfbits* __restrict__ h2) {
  const int m = blockIdx.x, tid = threadIdx.x;
  const size_t ro = (size_t)m * D_ + tid * 4;
  float4 v = *(const float4*)(x2 + ro);
  float s  = v.x + v.y + v.z + v.w;
  float s2 = v.x*v.x + v.y*v.y + v.z*v.z + v.w*v.w;
  float d0 = 0.f;
  blockreduce3(s, s2, d0);
  const float mean = s * (1.0f/1024.0f);
  const float var  = s2 * (1.0f/1024.0f) - mean*mean;
  const float rstd = rsqrtf(var + 1e-5f);
  float4 gg = *(const float4*)(gptr + tid * 4);
  float4 b2 = *(const float4*)(bptr + tid * 4);
  u16x4 hv;
  hv[0] = f2bf((v.x - mean) * rstd * gg.x + b2.x);
  hv[1] = f2bf((v.y - mean) * rstd * gg.y + b2.y);
  hv[2] = f2bf((v.z - mean) * rstd * gg.z + b2.z);
  hv[3] = f2bf((v.w - mean) * rstd * gg.w + b2.w);
  *(u16x4*)(h2 + ro) = hv;
}

// ---------- GEMM: C[M][N] = A[M][K](bf16,row-major) * Bt[N][K](bf16) with fused epilogues
// EPI 0: QKV (rope+gate, Q scaled 1/8; V -> V^T)   EPI 1: WO (x2 = x1 + C*gate)
// EPI 2: UP (gelu(C+up_b) -> bf16, ldc=1664)       EPI 3: DN (C+dn_b -> f32)
template <int EPI>
__global__ void __launch_bounds__(256, 2)
gemm_bt(const bfbits* __restrict__ A, int lda,
        const bfbits* __restrict__ Bt, int ldb, int K,
        const float* __restrict__ p0, const float* __restrict__ p1,
        float* __restrict__ fo0, bfbits* __restrict__ bo0,
        bfbits* __restrict__ bo1, bfbits* __restrict__ bo2) {
  __shared__ bfbits Asl[128 * 32];
  __shared__ bfbits Bsl[128 * 32];
  const int tid = threadIdx.x;
  const int lane = tid & 63, wave = tid >> 6;
  const int g = lane >> 4, l15 = lane & 15;
  const int wr = wave >> 1, wc = wave & 1;
  const int m0 = blockIdx.y * 128, n0 = blockIdx.x * 128;

  f32x4 acc[4][4] = {};

  for (int k0 = 0; k0 < K; k0 += 32) {
    #pragma unroll
    for (int p = 0; p < 2; ++p) {
      const int chunk = wave + p * 4;            // 0..7
      const int e = chunk * 512 + lane * 8;      // element in 128x32 tile
      const int row = e >> 5, ko = e & 31;
      gload16(A  + (size_t)(m0 + row) * lda + (k0 + ko), (char*)Asl + chunk * 1024);
      gload16(Bt + (size_t)(n0 + row) * ldb + (k0 + ko), (char*)Bsl + chunk * 1024);
    }
    __syncthreads();
    s16x8 af[4], bfr[4];
    #pragma unroll
    for (int i = 0; i < 4; ++i) af[i]  = *(const s16x8*)&Asl[(wr * 64 + i * 16 + l15) * 32 + g * 8];
    #pragma unroll
    for (int i = 0; i < 4; ++i) bfr[i] = *(const s16x8*)&Bsl[(wc * 64 + i * 16 + l15) * 32 + g * 8];
    #pragma unroll
    for (int i = 0; i < 4; ++i)
      #pragma unroll
      for (int j = 0; j < 4; ++j)
        acc[i][j] = __builtin_amdgcn_mfma_f32_16x16x32_bf16(af[i], bfr[j], acc[i][j], 0, 0, 0);
    __syncthreads();
  }

  const int b = m0 >> 11;
  const int trow0 = (m0 & 2047) + wr * 64;

  if constexpr (EPI == 0) {
    const float* gate = p0;
    const float* phase = p1;
    const int ncol0 = n0 + wc * 64;           // 64-aligned wave column base
    const int section = ncol0 >> 10;          // 0=Q 1=K 2=V
    const int hh = (ncol0 & 1023) >> 6;
    if (section == 2) {
      bfbits* vt = bo2;
      const size_t vhead = (size_t)(b * H_ + hh) * DH_ * T_;
      #pragma unroll
      for (int mi = 0; mi < 4; ++mi) {
        const int tb = trow0 + mi * 16 + g * 4;
        #pragma unroll
        for (int ni = 0; ni < 4; ++ni) {
          const int dh = ni * 16 + l15;
          #pragma unroll
          for (int r = 0; r < 4; ++r)
            vt[vhead + (size_t)dh * T_ + (tb + r)] = f2bf(acc[mi][ni][r]);
        }
      }
    } else {
      const float cc = cosf(phase[hh]);
      const float ssn = sinf(phase[hh]);
      const float qs = (section == 0) ? 0.125f : 1.0f;
      bfbits* dst = (section == 0) ? bo0 : bo1;
      const size_t head = (size_t)(b * H_ + hh) * T_ * DH_;
      #pragma unroll
      for (int mi = 0; mi < 4; ++mi) {
        const int tb = trow0 + mi * 16 + g * 4;
        float gv[4];
        #pragma unroll
        for (int r = 0; r < 4; ++r) gv[r] = gate[(size_t)b * T_ + tb + r] * qs;
        #pragma unroll
        for (int ni = 0; ni < 2; ++ni) {
          const int dh = ni * 16 + l15;
          #pragma unroll
          for (int r = 0; r < 4; ++r) {
            const float re = acc[mi][ni][r];
            const float im = acc[mi][ni + 2][r];
            const size_t idx = head + (size_t)(tb + r) * DH_ + dh;
            dst[idx]      = f2bf((re * cc - im * ssn) * gv[r]);
            dst[idx + 32] = f2bf((re * ssn + im * cc) * gv[r]);
          }
        }
      }
    }
  } else if constexpr (EPI == 1) {
    const float* gate = p0;
    const float* x1 = p1;
    float* x2 = fo0;
    #pragma unroll
    for (int mi = 0; mi < 4; ++mi) {
      const int m = m0 + wr * 64 + mi * 16 + g * 4;
      float gv[4];
      #pragma unroll
      for (int r = 0; r < 4; ++r) gv[r] = gate[m + r];
      #pragma unroll
      for (int ni = 0; ni < 4; ++ni) {
        const int n = n0 + wc * 64 + ni * 16 + l15;
        #pragma unroll
        for (int r = 0; r < 4; ++r) {
          const size_t idx = (size_t)(m + r) * D_ + n;
          x2[idx] = x1[idx] + acc[mi][ni][r] * gv[r];
        }
      }
    }
  } else if constexpr (EPI == 2) {
    const float* upb = p0;
    bfbits* outm = bo0;
    #pragma unroll
    for (int mi = 0; mi < 4; ++mi) {
      const int m = m0 + wr * 64 + mi * 16 + g * 4;
      #pragma unroll
      for (int ni = 0; ni < 4; ++ni) {
        const int n = n0 + wc * 64 + ni * 16 + l15;
        const float bb = upb[n];
        #pragma unroll
        for (int r = 0; r < 4; ++r) {
          float v = acc[mi][ni][r] + bb;
          v = 0.5f * v * (1.0f + erff(v * 0.70710678118654752f));
          outm[(size_t)(m + r) * DFFP_ + n] = f2bf(v);
        }
      }
    }
  } else {
    const float* dnb = p0;
    float* outf = fo0;
    #pragma unroll
    for (int mi = 0; mi < 4; ++mi) {
      const int m = m0 + wr * 64 + mi * 16 + g * 4;
      #pragma unroll
      for (int ni = 0; ni < 4; ++ni) {
        const int n = n0 + wc * 64 + ni * 16 + l15;
        const float bb = dnb[n];
        #pragma unroll
        for (int r = 0; r < 4; ++r)
          outf[(size_t)(m + r) * D_ + n] = acc[mi][ni][r] + bb;
      }
    }
  }
}

// ---------- flash attention v2: 4 waves/block, 128 q-rows/block, KVBLK=64
// K and V^T staged in LDS (double-buffered, XOR-swizzled via pre-swizzled
// global source for global_load_lds). Wave w owns q rows [qb0+32w, qb0+32w+32)
// as two 16-row MFMA tiles. Swapped QK^T (S^T = K*Q^T) keeps softmax lane-local
// in k; PV computes O^T = V^T * P^T.
__global__ void __launch_bounds__(256, 2)
attn_kernel(const bfbits* __restrict__ Qb, const bfbits* __restrict__ Kb,
            const bfbits* __restrict__ Vt, bfbits* __restrict__ AO) {
  __shared__ bfbits Kl[2][64 * 64];
  __shared__ bfbits Vl[2][64 * 64];
  const int bh = blockIdx.y;   // 0..31
  const int qb0 = ((int)gridDim.x - 1 - (int)blockIdx.x) * 128;  // heavy blocks first
  const int tid = threadIdx.x, lane = tid & 63, wq = tid >> 6;
  const int g = lane >> 4, l15 = lane & 15;

  const bfbits* Qp = Qb + ((size_t)bh * T_ + qb0 + wq * 32) * DH_;
  const bfbits* Kp = Kb + (size_t)bh * T_ * DH_;
  const bfbits* Vp = Vt + (size_t)bh * DH_ * T_;

  // Q fragments: qi in {0,1} -> rows qb0+wq*32+qi*16+l15, two dh halves
  s16x8 qf[2][2];
  #pragma unroll
  for (int qi = 0; qi < 2; ++qi) {
    qf[qi][0] = *(const s16x8*)(Qp + (qi * 16 + l15) * DH_ + g * 8);
    qf[qi][1] = *(const s16x8*)(Qp + (qi * 16 + l15) * DH_ + 32 + g * 8);
  }

  f32x4 o[2][4] = {};
  float mrun[2] = {-INFINITY, -INFINITY};
  float lrun[2] = {0.f, 0.f};

  const int nk = (qb0 + 128) >> 6;          // k-tiles for this block
  const int my_kend = qb0 + wq * 32 + 32;   // causal end for this wave

  // stage tile (k0) into parity p. LDS chunk c holds global chunk c^(row&7)
  // (XOR swizzle applied on the SOURCE address; LDS dest stays linear).
  auto stage = [&](int k0, int p) {
    #pragma unroll
    for (int ii = 0; ii < 2; ++ii) {
      const int cb = ii * 256 + wq * 64;      // wave-uniform chunk base
      const int c = cb + lane;
      const int row = c >> 3;
      const int sc = ((c & 7) ^ (row & 7)) * 8;   // swizzled source elem offset
      gload16(Kp + (size_t)(k0 + row) * DH_ + sc, (char*)(&Kl[p][0]) + cb * 16);
      gload16(Vp + (size_t)row * T_ + (k0 + sc),  (char*)(&Vl[p][0]) + cb * 16);
    }
  };

  stage(0, 0);
  __syncthreads();

  for (int t = 0; t < nk; ++t) {
    const int p = t & 1;
    if (t + 1 < nk) stage((t + 1) << 6, p ^ 1);
    const int k0 = t << 6;
    if (k0 < my_kend) {
      // ---- QK^T: S^T tile [64 k][16 q] per q-tile ----
      f32x4 st[2][4];
      #pragma unroll
      for (int kt = 0; kt < 4; ++kt) {
        const int krow = kt * 16 + l15;
        const int rs = krow & 7;
        const s16x8 ka  = *(const s16x8*)&Kl[p][krow * 64 + ((0 + g) ^ rs) * 8];
        const s16x8 kb2 = *(const s16x8*)&Kl[p][krow * 64 + ((4 + g) ^ rs) * 8];
        #pragma unroll
        for (int qi = 0; qi < 2; ++qi) {
          f32x4 z = {0.f, 0.f, 0.f, 0.f};
          z = __builtin_amdgcn_mfma_f32_16x16x32_bf16(ka,  qf[qi][0], z, 0, 0, 0);
          z = __builtin_amdgcn_mfma_f32_16x16x32_bf16(kb2, qf[qi][1], z, 0, 0, 0);
          st[qi][kt] = z;
        }
      }
      // ---- online softmax (lane-local in k; q = l15) ----
      s16x8 pf[2][2];
      #pragma unroll
      for (int qi = 0; qi < 2; ++qi) {
        const int qrow = qb0 + wq * 32 + qi * 16 + l15;
        if (k0 + 63 > qrow) {               // causal mask on diagonal tiles
          #pragma unroll
          for (int kt = 0; kt < 4; ++kt)
            #pragma unroll
            for (int r = 0; r < 4; ++r)
              if (k0 + kt * 16 + g * 4 + r > qrow) st[qi][kt][r] = -1e9f;
        }
        float mx = -INFINITY;
        #pragma unroll
        for (int kt = 0; kt < 4; ++kt)
          #pragma unroll
          for (int r = 0; r < 4; ++r) mx = fmaxf(mx, st[qi][kt][r]);
        mx = fmaxf(mx, __shfl_xor(mx, 16));
        mx = fmaxf(mx, __shfl_xor(mx, 32));
        const float mnew = fmaxf(mrun[qi], mx);
        float sum = 0.f;
        #pragma unroll
        for (int kt = 0; kt < 4; ++kt)
          #pragma unroll
          for (int r = 0; r < 4; ++r) {
            const float e = __expf(st[qi][kt][r] - mnew);
            st[qi][kt][r] = e;
            sum += e;
          }
        sum += __shfl_xor(sum, 16);
        sum += __shfl_xor(sum, 32);
        const float alpha = __expf(mrun[qi] - mnew);
        mrun[qi] = mnew;
        lrun[qi] = lrun[qi] * alpha + sum;
        #pragma unroll
        for (int dt = 0; dt < 4; ++dt) {
          o[qi][dt][0] *= alpha; o[qi][dt][1] *= alpha;
          o[qi][dt][2] *= alpha; o[qi][dt][3] *= alpha;
        }
        #pragma unroll
        for (int ks = 0; ks < 2; ++ks) {
          s16x8 pv;
          #pragma unroll
          for (int r = 0; r < 4; ++r) {
            pv[r]     = (short)f2bf(st[qi][2 * ks][r]);
            pv[4 + r] = (short)f2bf(st[qi][2 * ks + 1][r]);
          }
          pf[qi][ks] = pv;
        }
      }
      // ---- PV: O^T += V^T * P^T ----
      #pragma unroll
      for (int dt = 0; dt < 4; ++dt) {
        const int vrow = dt * 16 + l15;
        const int rs = vrow & 7;
        #pragma unroll
        for (int ks = 0; ks < 2; ++ks) {
          const u16x4 vlo = *(const u16x4*)&Vl[p][vrow * 64 + ((ks * 4 + 0 + (g >> 1)) ^ rs) * 8 + (g & 1) * 4];
          const u16x4 vhi = *(const u16x4*)&Vl[p][vrow * 64 + ((ks * 4 + 2 + (g >> 1)) ^ rs) * 8 + (g & 1) * 4];
          s16x8 vf;
          vf[0] = (short)vlo[0]; vf[1] = (short)vlo[1]; vf[2] = (short)vlo[2]; vf[3] = (short)vlo[3];
          vf[4] = (short)vhi[0]; vf[5] = (short)vhi[1]; vf[6] = (short)vhi[2]; vf[7] = (short)vhi[3];
          o[0][dt] = __builtin_amdgcn_mfma_f32_16x16x32_bf16(vf, pf[0][ks], o[0][dt], 0, 0, 0);
          o[1][dt] = __builtin_amdgcn_mfma_f32_16x16x32_bf16(vf, pf[1][ks], o[1][dt], 0, 0, 0);
        }
      }
    }
    __syncthreads();
  }

  const int b = bh >> 4, hh = bh & 15;
  #pragma unroll
  for (int qi = 0; qi < 2; ++qi) {
    const float inv = 1.0f / lrun[qi];
    bfbits* dst = AO + ((size_t)b * T_ + qb0 + wq * 32 + qi * 16 + l15) * D_ + hh * DH_;
    #pragma unroll
    for (int dt = 0; dt < 4; ++dt)
      #pragma unroll
      for (int r = 0; r < 4; ++r)
        dst[dt * 16 + g * 4 + r] = f2bf(o[qi][dt][r] * inv);
  }
}

// ---------- pooling / commit / center / final ----------
__global__ __launch_bounds__(256)
void pool_part(const float* __restrict__ x2, float* __restrict__ part) {
  const int s = blockIdx.x, b = blockIdx.y, tid = threadIdx.x;
  const float* base = x2 + ((size_t)b * T_ + s * 128) * D_ + tid * 4;
  float ax = 0, ay = 0, az = 0, aw = 0;
  for (int t = 0; t < 128; ++t) {
    float4 v = *(const float4*)(base + (size_t)t * D_);
    ax += v.x; ay += v.y; az += v.z; aw += v.w;
  }
  float4 ov; ov.x = ax; ov.y = ay; ov.z = az; ov.w = aw;
  *(float4*)(part + (size_t)(b * 16 + s) * D_ + tid * 4) = ov;
}

__global__ __launch_bounds__(256)
void pool_fin(const float* __restrict__ part, float* __restrict__ pool) {
  const int idx = blockIdx.x * 256 + threadIdx.x; // 0..2047
  const int b = idx >> 10, d = idx & 1023;
  float s = 0.f;
  for (int i = 0; i < 16; ++i) s += part[(size_t)(b * 16 + i) * D_ + d];
  pool[idx] = s * (1.0f / 2048.0f);
}

__global__ __launch_bounds__(256)
void commit_kernel(const float* __restrict__ pool, const float* __restrict__ cw,
                   const float* __restrict__ cb0, float* __restrict__ cmt,
                   float* __restrict__ out_cmt) {
  const int b = blockIdx.x, tid = threadIdx.x;
  float4 p = *(const float4*)(pool + b * 1024 + tid * 4);
  float4 w = *(const float4*)(cw + tid * 4);
  float s = p.x * w.x + p.y * w.y + p.z * w.z + p.w * w.w;
  #pragma unroll
  for (int o = 32; o > 0; o >>= 1) s += __shfl_xor(s, o);
  __shared__ float ls[4];
  if ((tid & 63) == 0) ls[tid >> 6] = s;
  __syncthreads();
  if (tid == 0) {
    const float t = ls[0] + ls[1] + ls[2] + ls[3] + cb0[0];
    const float v = 1.0f / (1.0f + expf(-t));
    cmt[b] = v; out_cmt[b] = v;
  }
}

__global__ __launch_bounds__(256)
void center_kernel(const float* __restrict__ pool, const float* __restrict__ cpw,
                   const float* __restrict__ cpb, float* __restrict__ outc) {
  const int idx = blockIdx.x * 256 + threadIdx.x; // 0..2047
  const int b = idx >> 10, c = idx & 1023;
  const float* pb = pool + b * 1024;
  float s = 0.f;
  for (int d = 0; d < 1024; ++d) s += pb[d] * cpw[(size_t)d * 1024 + c];
  outc[idx] = tanhf(s + cpb[c]);
}

__global__ __launch_bounds__(256)
void final_kernel(const float* __restrict__ x2, const float* __restrict__ ff,
                  const float* __restrict__ gate, const float* __restrict__ cmt,
                  float* __restrict__ outx) {
  const size_t i = (size_t)blockIdx.x * 256 + threadIdx.x; // * 4 elements
  const int m = (int)(i >> 8);
  const int b = m >> 11;
  const float k = cmt[b] * gate[m];
  float4 xv = *(const float4*)(x2 + i * 4);
  float4 fv = *(const float4*)(ff + i * 4);
  float4 ov;
  ov.x = xv.x + k * fv.x; ov.y = xv.y + k * fv.y;
  ov.z = xv.z + k * fv.z; ov.w = xv.w + k * fv.w;
  *(float4*)(outx + i * 4) = ov;
}

// ---------------- host launcher ----------------
extern "C" void kernel_launch(void* const* d_in, const int* in_sizes, int n_in,
                              void* d_out, int out_size, void* d_ws, size_t ws_size,
                              hipStream_t stream) {
  (void)in_sizes; (void)n_in; (void)out_size; (void)ws_size;
  const float* x       = (const float*)d_in[0];
  const float* cfa     = (const float*)d_in[1];
  const float* gate_w  = (const float*)d_in[3];
  const float* gate_b  = (const float*)d_in[4];
  const float* cb_w    = (const float*)d_in[5];
  const float* nf_g    = (const float*)d_in[6];
  const float* nf_b    = (const float*)d_in[7];
  const float* wq      = (const float*)d_in[8];
  const float* wk      = (const float*)d_in[9];
  const float* wv      = (const float*)d_in[10];
  const float* wo      = (const float*)d_in[11];
  const float* phase   = (const float*)d_in[12];
  const float* nb_g    = (const float*)d_in[13];
  const float* nb_b    = (const float*)d_in[14];
  const float* up_w    = (const float*)d_in[15];
  const float* up_b    = (const float*)d_in[16];
  const float* dn_w    = (const float*)d_in[17];
  const float* dn_b    = (const float*)d_in[18];
  const float* cmt_w   = (const float*)d_in[19];
  const float* cmt_b   = (const float*)d_in[20];
  const float* cproj_w = (const float*)d_in[21];
  const float* cproj_b = (const float*)d_in[22];
  const float* bcast_w = (const float*)d_in[23];
  const float* bcast_b = (const float*)d_in[24];

  char* ws = (char*)d_ws;
  float*  x1     = (float*)(ws + OFF_X1);
  float*  ff     = (float*)(ws + OFF_X1);     // alias: x1 dead after WO
  bfbits* h      = (bfbits*)(ws + OFF_H);
  bfbits* h2     = (bfbits*)(ws + OFF_H);     // alias: h dead after QKV
  bfbits* qb     = (bfbits*)(ws + OFF_Q);
  bfbits* kb     = (bfbits*)(ws + OFF_K);
  bfbits* vt     = (bfbits*)(ws + OFF_VT);
  bfbits* ffmid  = (bfbits*)(ws + OFF_Q);     // alias: Q/K dead after attention
  bfbits* ao     = (bfbits*)(ws + OFF_AO);
  float*  x2     = (float*)(ws + OFF_X2);
  bfbits* wqkv_t = (bfbits*)(ws + OFF_WQKV);
  bfbits* wo_t   = (bfbits*)(ws + OFF_WO);
  bfbits* wup_t  = (bfbits*)(ws + OFF_WUP);
  bfbits* wdn_t  = (bfbits*)(ws + OFF_WDN);
  float*  bvec   = (float*)(ws + OFF_BVEC);
  float*  cbv    = (float*)(ws + OFF_CBV);
  float*  gate   = (float*)(ws + OFF_GATE);
  float*  part   = (float*)(ws + OFF_PART);
  float*  pool   = (float*)(ws + OFF_POOL);
  float*  cmt    = (float*)(ws + OFF_CMT);

  float* outx   = (float*)d_out;
  float* outc   = outx + NELEM_X;          // center [B][DC]
  float* outg   = outc + B_ * DC_;         // gate [B][T]
  float* outcmt = outg + B_ * T_;          // commit [B]

  // weight prep (B^T bf16)
  transpose_w<<<dim3(32, 32), 256, 0, stream>>>(wq, wqkv_t,                1024, 1024, 1024, 1024);
  transpose_w<<<dim3(32, 32), 256, 0, stream>>>(wk, wqkv_t + 1024 * 1024,  1024, 1024, 1024, 1024);
  transpose_w<<<dim3(32, 32), 256, 0, stream>>>(wv, wqkv_t + 2048 * 1024,  1024, 1024, 1024, 1024);
  transpose_w<<<dim3(32, 32), 256, 0, stream>>>(wo, wo_t,                  1024, 1024, 1024, 1024);
  transpose_w<<<dim3(32, 52), 256, 0, stream>>>(up_w, wup_t,               1024, DFF_, 1024, DFFP_);
  transpose_w<<<dim3(52, 32), 256, 0, stream>>>(dn_w, wdn_t,               DFF_, 1024, DFFP_, 1024);

  bvec_kernel<<<8, 256, 0, stream>>>(cfa, bcast_w, bcast_b, bvec);
  cb_kernel<<<B_, 256, 0, stream>>>(cfa, cb_w, cbv);

  ln1_kernel<<<MTOT, 256, 0, stream>>>(x, bvec, cbv, gate_w, gate_b, nf_g, nf_b,
                                       x1, h, gate, outg);

  gemm_bt<0><<<dim3(24, 32), 256, 0, stream>>>(h, 1024, wqkv_t, 1024, 1024,
                                               gate, phase, nullptr, qb, kb, vt);

  attn_kernel<<<dim3(16, 32), 256, 0, stream>>>(qb, kb, vt, ao);

  gemm_bt<1><<<dim3(8, 32), 256, 0, stream>>>(ao, 1024, wo_t, 1024, 1024,
                                              gate, x1, x2, nullptr, nullptr, nullptr);

  ln2_kernel<<<MTOT, 256, 0, stream>>>(x2, nb_g, nb_b, h2);

  gemm_bt<2><<<dim3(13, 32), 256, 0, stream>>>(h2, 1024, wup_t, 1024, 1024,
                                               up_b, nullptr, nullptr, ffmid, nullptr, nullptr);

  gemm_bt<3><<<dim3(8, 32), 256, 0, stream>>>(ffmid, DFFP_, wdn_t, DFFP_, DFFP_,
                                              dn_b, nullptr, ff, nullptr, nullptr, nullptr);

  pool_part<<<dim3(16, B_), 256, 0, stream>>>(x2, part);
  pool_fin<<<8, 256, 0, stream>>>(part, pool);
  commit_kernel<<<B_, 256, 0, stream>>>(pool, cmt_w, cmt_b, cmt, outcmt);
  center_kernel<<<8, 256, 0, stream>>>(pool, cproj_w, cproj_b, outc);

  final_kernel<<<4096, 256, 0, stream>>>(x2, ff, gate, cmt, outx);
}

// Round 3
// 320.377 us; speedup vs baseline: 1.8578x; 1.0446x over previous
//
#include <hip/hip_runtime.h>
#include <math.h>

// ---- problem constants ----
#define B_   2
#define T_   2048
#define D_   1024
#define H_   16
#define DH_  64
#define DC_  1024
#define DFF_ 1656
#define DFFP_ 1664
#define MTOT 4096          // B_*T_
#define NELEM_X 4194304ull // B*T*D

typedef short s16x8 __attribute__((ext_vector_type(8)));
typedef unsigned short u16x4 __attribute__((ext_vector_type(4)));
typedef float f32x4 __attribute__((ext_vector_type(4)));
typedef unsigned short bfbits;

__device__ __forceinline__ bfbits f2bf(float f) {
  unsigned int u = __builtin_bit_cast(unsigned int, f);
  u += 0x7fffu + ((u >> 16) & 1u);          // RNE
  return (bfbits)(u >> 16);
}
__device__ __forceinline__ float bf2f(bfbits b) {
  unsigned int u = ((unsigned int)b) << 16;
  return __builtin_bit_cast(float, u);
}

__device__ __forceinline__ float vexp2(float x) {   // 2^x via HW transcendental
  float r;
  asm("v_exp_f32 %0, %1" : "=v"(r) : "v"(x));
  return r;
}
__device__ __forceinline__ unsigned pkbf(float lo, float hi) { // 2xbf16 pack, RNE
  unsigned r;
  asm("v_cvt_pk_bf16_f32 %0, %1, %2" : "=v"(r) : "v"(lo), "v"(hi));
  return r;
}

__device__ __forceinline__ void gload16(const void* g, void* l) {
  __builtin_amdgcn_global_load_lds(
      (__attribute__((address_space(1))) void*)g,
      (__attribute__((address_space(3))) void*)l, 16, 0, 0);
}

// ---------- workspace offsets (bytes) ----------
constexpr size_t OFF_X1   = 0;                                  // f32 x1 ; later ff
constexpr size_t OFF_H    = OFF_X1 + 4ull*NELEM_X;              // bf16 h ; later h2
constexpr size_t OFF_Q    = OFF_H  + 2ull*NELEM_X;              // bf16 Q [BH][T][64] ; later ffmid
constexpr size_t OFF_K    = OFF_Q  + 2ull*NELEM_X;              // bf16 K [BH][T][64]
constexpr size_t OFF_VT   = OFF_K  + 2ull*NELEM_X;              // bf16 V^T [BH][64][T]
constexpr size_t OFF_AO   = OFF_VT + 2ull*NELEM_X;              // bf16 attn out [M][D]
constexpr size_t OFF_X2   = OFF_AO + 2ull*NELEM_X;              // f32 x2
constexpr size_t OFF_WQKV = OFF_X2 + 4ull*NELEM_X;              // bf16 [3072][1024]
constexpr size_t OFF_WO   = OFF_WQKV + 3072ull*1024*2;          // bf16 [1024][1024]
constexpr size_t OFF_WUP  = OFF_WO   + 1024ull*1024*2;          // bf16 [1664][1024]
constexpr size_t OFF_WDN  = OFF_WUP  + 1664ull*1024*2;          // bf16 [1024][1664]
constexpr size_t OFF_BVEC = OFF_WDN  + 1024ull*1664*2;          // f32 [B][D]
constexpr size_t OFF_CBV  = OFF_BVEC + 2048ull*4;               // f32 [B]
constexpr size_t OFF_GATE = OFF_CBV  + 256;                     // f32 [M]
constexpr size_t OFF_PART = OFF_GATE + 4096ull*4;               // f32 [32][1024]
constexpr size_t OFF_POOL = OFF_PART + 32ull*1024*4;            // f32 [B][D]
constexpr size_t OFF_CMT  = OFF_POOL + 2048ull*4;               // f32 [B]

// ---------- transpose f32 [R][C] -> bf16 [Npad][Rpad], dst[n][k] = (k<R && n<C) ? src[k][n] : 0
__global__ __launch_bounds__(256)
void transpose_w(const float* __restrict__ src, bfbits* __restrict__ dst,
                 int R, int C, int Rpad, int Npad) {
  __shared__ float tile[32][33];
  const int kb = blockIdx.x * 32, nb = blockIdx.y * 32;
  const int tx = threadIdx.x & 31, ty = threadIdx.x >> 5;
  for (int i = ty; i < 32; i += 8) {
    const int k = kb + i, n = nb + tx;
    tile[i][tx] = (k < R && n < C) ? src[(size_t)k * C + n] : 0.f;
  }
  __syncthreads();
  for (int i = ty; i < 32; i += 8) {
    const int n = nb + i, k = kb + tx;
    if (n < Npad && k < Rpad) dst[(size_t)n * Rpad + k] = f2bf(tile[tx][i]);
  }
}

// ---------- bvec[b][d] = center@bcast_w + bcast_b
__global__ __launch_bounds__(256)
void bvec_kernel(const float* __restrict__ cfa, const float* __restrict__ bw,
                 const float* __restrict__ bb, float* __restrict__ bvec) {
  const int idx = blockIdx.x * 256 + threadIdx.x; // 0..2047
  const int b = idx >> 10, d = idx & 1023;
  const float* a = cfa + b * 1024;
  float s = 0.f;
  for (int c = 0; c < 1024; ++c) s += a[c] * bw[(size_t)c * 1024 + d];
  bvec[idx] = s + bb[d];
}

__global__ __launch_bounds__(256)
void cb_kernel(const float* __restrict__ cfa, const float* __restrict__ cbw,
               float* __restrict__ cbv) {
  const int b = blockIdx.x, tid = threadIdx.x;
  float4 a = *(const float4*)(cfa + b * 1024 + tid * 4);
  float4 w = *(const float4*)(cbw + tid * 4);
  float s = a.x * w.x + a.y * w.y + a.z * w.z + a.w * w.w;
  #pragma unroll
  for (int o = 32; o > 0; o >>= 1) s += __shfl_xor(s, o);
  __shared__ float ls[4];
  if ((tid & 63) == 0) ls[tid >> 6] = s;
  __syncthreads();
  if (tid == 0) cbv[b] = ls[0] + ls[1] + ls[2] + ls[3];
}

__device__ __forceinline__ void blockreduce3(float& a, float& b, float& c) {
  #pragma unroll
  for (int o = 32; o > 0; o >>= 1) {
    a += __shfl_xor(a, o);
    b += __shfl_xor(b, o);
    c += __shfl_xor(c, o);
  }
  __shared__ float ls[3][4];
  const int lane = threadIdx.x & 63, w = threadIdx.x >> 6;
  if (lane == 0) { ls[0][w] = a; ls[1][w] = b; ls[2][w] = c; }
  __syncthreads();
  a = ls[0][0] + ls[0][1] + ls[0][2] + ls[0][3];
  b = ls[1][0] + ls[1][1] + ls[1][2] + ls[1][3];
  c = ls[2][0] + ls[2][1] + ls[2][2] + ls[2][3];
}

// ---------- fused: x1 = x + bvec ; gate ; LN(x1) -> h (bf16)
__global__ __launch_bounds__(256)
void ln1_kernel(const float* __restrict__ x, const float* __restrict__ bvec,
                const float* __restrict__ cbv, const float* __restrict__ gw,
                const float* __restrict__ gb, const float* __restrict__ nfg,
                const float* __restrict__ nfb, float* __restrict__ x1,
                bfbits* __restrict__ h, float* __restrict__ gate_ws,
                float* __restrict__ gate_out) {
  const int m = blockIdx.x, tid = threadIdx.x, b = m >> 11;
  const size_t ro = (size_t)m * D_ + tid * 4;
  float4 xv = *(const float4*)(x + ro);
  float4 bv = *(const float4*)(bvec + b * D_ + tid * 4);
  float4 v;
  v.x = xv.x + bv.x; v.y = xv.y + bv.y; v.z = xv.z + bv.z; v.w = xv.w + bv.w;
  float4 g4 = *(const float4*)(gw + tid * 4);
  float s  = v.x + v.y + v.z + v.w;
  float s2 = v.x*v.x + v.y*v.y + v.z*v.z + v.w*v.w;
  float dg = v.x*g4.x + v.y*g4.y + v.z*g4.z + v.w*g4.w;
  blockreduce3(s, s2, dg);
  const float mean = s * (1.0f/1024.0f);
  const float var  = s2 * (1.0f/1024.0f) - mean*mean;
  const float rstd = rsqrtf(var + 1e-5f);
  if (tid == 0) {
    const float logits = dg + gb[0] + cbv[b];
    const float prob = 1.0f / (1.0f + expf(-logits));
    const float hard = prob > 0.5f ? 1.0f : 0.0f;
    const float gv = (hard - prob) + prob;
    gate_ws[m] = gv; gate_out[m] = gv;
  }
  *(float4*)(x1 + ro) = v;
  float4 gg = *(const float4*)(nfg + tid * 4);
  float4 b2 = *(const float4*)(nfb + tid * 4);
  u16x4 hv;
  hv[0] = f2bf((v.x - mean) * rstd * gg.x + b2.x);
  hv[1] = f2bf((v.y - mean) * rstd * gg.y + b2.y);
  hv[2] = f2bf((v.z - mean) * rstd * gg.z + b2.z);
  hv[3] = f2bf((v.w - mean) * rstd * gg.w + b2.w);
  *(u16x4*)(h + ro) = hv;
}

__global__ __launch_bounds__(256)
void ln2_kernel(const float* __restrict__ x2, const float* __restrict__ gptr,
                const float* __restrict__ bptr, bfbits* __restrict__ h2) {
  const int m = blockIdx.x, tid = threadIdx.x;
  const size_t ro = (size_t)m * D_ + tid * 4;
  float4 v = *(const float4*)(x2 + ro);
  float s  = v.x + v.y + v.z + v.w;
  float s2 = v.x*v.x + v.y*v.y + v.z*v.z + v.w*v.w;
  float d0 = 0.f;
  blockreduce3(s, s2, d0);
  const float mean = s * (1.0f/1024.0f);
  const float var  = s2 * (1.0f/1024.0f) - mean*mean;
  const float rstd = rsqrtf(var + 1e-5f);
  float4 gg = *(const float4*)(gptr + tid * 4);
  float4 b2 = *(const float4*)(bptr + tid * 4);
  u16x4 hv;
  hv[0] = f2bf((v.x - mean) * rstd * gg.x + b2.x);
  hv[1] = f2bf((v.y - mean) * rstd * gg.y + b2.y);
  hv[2] = f2bf((v.z - mean) * rstd * gg.z + b2.z);
  hv[3] = f2bf((v.w - mean) * rstd * gg.w + b2.w);
  *(u16x4*)(h2 + ro) = hv;
}

// ---------- GEMM: C[M][N] = A[M][K](bf16,row-major) * Bt[N][K](bf16) with fused epilogues
// EPI 0: QKV (rope+gate, Q scaled (1/8)*log2e; V -> V^T)   EPI 1: WO (x2 = x1 + C*gate)
// EPI 2: UP (gelu(C+up_b) -> bf16, ldc=1664)               EPI 3: DN (C+dn_b -> f32)
template <int EPI>
__global__ void __launch_bounds__(256, 2)
gemm_bt(const bfbits* __restrict__ A, int lda,
        const bfbits* __restrict__ Bt, int ldb, int K,
        const float* __restrict__ p0, const float* __restrict__ p1,
        float* __restrict__ fo0, bfbits* __restrict__ bo0,
        bfbits* __restrict__ bo1, bfbits* __restrict__ bo2) {
  __shared__ bfbits Asl[128 * 32];
  __shared__ bfbits Bsl[128 * 32];
  const int tid = threadIdx.x;
  const int lane = tid & 63, wave = tid >> 6;
  const int g = lane >> 4, l15 = lane & 15;
  const int wr = wave >> 1, wc = wave & 1;
  const int m0 = blockIdx.y * 128, n0 = blockIdx.x * 128;

  f32x4 acc[4][4] = {};

  for (int k0 = 0; k0 < K; k0 += 32) {
    #pragma unroll
    for (int p = 0; p < 2; ++p) {
      const int chunk = wave + p * 4;            // 0..7
      const int e = chunk * 512 + lane * 8;      // element in 128x32 tile
      const int row = e >> 5, ko = e & 31;
      gload16(A  + (size_t)(m0 + row) * lda + (k0 + ko), (char*)Asl + chunk * 1024);
      gload16(Bt + (size_t)(n0 + row) * ldb + (k0 + ko), (char*)Bsl + chunk * 1024);
    }
    __syncthreads();
    s16x8 af[4], bfr[4];
    #pragma unroll
    for (int i = 0; i < 4; ++i) af[i]  = *(const s16x8*)&Asl[(wr * 64 + i * 16 + l15) * 32 + g * 8];
    #pragma unroll
    for (int i = 0; i < 4; ++i) bfr[i] = *(const s16x8*)&Bsl[(wc * 64 + i * 16 + l15) * 32 + g * 8];
    #pragma unroll
    for (int i = 0; i < 4; ++i)
      #pragma unroll
      for (int j = 0; j < 4; ++j)
        acc[i][j] = __builtin_amdgcn_mfma_f32_16x16x32_bf16(af[i], bfr[j], acc[i][j], 0, 0, 0);
    __syncthreads();
  }

  const int b = m0 >> 11;
  const int trow0 = (m0 & 2047) + wr * 64;

  if constexpr (EPI == 0) {
    const float* gate = p0;
    const float* phase = p1;
    const int ncol0 = n0 + wc * 64;           // 64-aligned wave column base
    const int section = ncol0 >> 10;          // 0=Q 1=K 2=V
    const int hh = (ncol0 & 1023) >> 6;
    if (section == 2) {
      bfbits* vt = bo2;
      const size_t vhead = (size_t)(b * H_ + hh) * DH_ * T_;
      #pragma unroll
      for (int mi = 0; mi < 4; ++mi) {
        const int tb = trow0 + mi * 16 + g * 4;
        #pragma unroll
        for (int ni = 0; ni < 4; ++ni) {
          const int dh = ni * 16 + l15;
          #pragma unroll
          for (int r = 0; r < 4; ++r)
            vt[vhead + (size_t)dh * T_ + (tb + r)] = f2bf(acc[mi][ni][r]);
        }
      }
    } else {
      const float cc = cosf(phase[hh]);
      const float ssn = sinf(phase[hh]);
      // Q side carries 1/sqrt(DH) AND log2(e) so attention scores are in
      // exp2 domain (softmax uses raw v_exp_f32).
      const float qs = (section == 0) ? 0.125f * 1.44269504088896341f : 1.0f;
      bfbits* dst = (section == 0) ? bo0 : bo1;
      const size_t head = (size_t)(b * H_ + hh) * T_ * DH_;
      #pragma unroll
      for (int mi = 0; mi < 4; ++mi) {
        const int tb = trow0 + mi * 16 + g * 4;
        float gv[4];
        #pragma unroll
        for (int r = 0; r < 4; ++r) gv[r] = gate[(size_t)b * T_ + tb + r] * qs;
        #pragma unroll
        for (int ni = 0; ni < 2; ++ni) {
          const int dh = ni * 16 + l15;
          #pragma unroll
          for (int r = 0; r < 4; ++r) {
            const float re = acc[mi][ni][r];
            const float im = acc[mi][ni + 2][r];
            const size_t idx = head + (size_t)(tb + r) * DH_ + dh;
            dst[idx]      = f2bf((re * cc - im * ssn) * gv[r]);
            dst[idx + 32] = f2bf((re * ssn + im * cc) * gv[r]);
          }
        }
      }
    }
  } else if constexpr (EPI == 1) {
    const float* gate = p0;
    const float* x1 = p1;
    float* x2 = fo0;
    #pragma unroll
    for (int mi = 0; mi < 4; ++mi) {
      const int m = m0 + wr * 64 + mi * 16 + g * 4;
      float gv[4];
      #pragma unroll
      for (int r = 0; r < 4; ++r) gv[r] = gate[m + r];
      #pragma unroll
      for (int ni = 0; ni < 4; ++ni) {
        const int n = n0 + wc * 64 + ni * 16 + l15;
        #pragma unroll
        for (int r = 0; r < 4; ++r) {
          const size_t idx = (size_t)(m + r) * D_ + n;
          x2[idx] = x1[idx] + acc[mi][ni][r] * gv[r];
        }
      }
    }
  } else if constexpr (EPI == 2) {
    const float* upb = p0;
    bfbits* outm = bo0;
    #pragma unroll
    for (int mi = 0; mi < 4; ++mi) {
      const int m = m0 + wr * 64 + mi * 16 + g * 4;
      #pragma unroll
      for (int ni = 0; ni < 4; ++ni) {
        const int n = n0 + wc * 64 + ni * 16 + l15;
        const float bb = upb[n];
        #pragma unroll
        for (int r = 0; r < 4; ++r) {
          float v = acc[mi][ni][r] + bb;
          v = 0.5f * v * (1.0f + erff(v * 0.70710678118654752f));
          outm[(size_t)(m + r) * DFFP_ + n] = f2bf(v);
        }
      }
    }
  } else {
    const float* dnb = p0;
    float* outf = fo0;
    #pragma unroll
    for (int mi = 0; mi < 4; ++mi) {
      const int m = m0 + wr * 64 + mi * 16 + g * 4;
      #pragma unroll
      for (int ni = 0; ni < 4; ++ni) {
        const int n = n0 + wc * 64 + ni * 16 + l15;
        const float bb = dnb[n];
        #pragma unroll
        for (int r = 0; r < 4; ++r)
          outf[(size_t)(m + r) * D_ + n] = acc[mi][ni][r] + bb;
      }
    }
  }
}

// ---------- flash attention v3: 2 waves/block, 64 q-rows/block, KVBLK=64
// grid = 1024 blocks, rank-paired so concurrent blocks sum to ~constant work.
// K and V^T staged in LDS (double-buffered, XOR-swizzled source for
// global_load_lds). Softmax in exp2 domain (log2e folded into Q), defer-max
// rescale (THR=8), v_cvt_pk_bf16_f32 P-pack.
__global__ void __launch_bounds__(128, 2)
attn_kernel(const bfbits* __restrict__ Qb, const bfbits* __restrict__ Kb,
            const bfbits* __restrict__ Vt, bfbits* __restrict__ AO) {
  __shared__ bfbits Kl[2][64 * 64];
  __shared__ bfbits Vl[2][64 * 64];
  const int pid = blockIdx.x;                       // 0..1023
  const int rank = (pid < 512) ? pid : 1535 - pid;  // pair heavy+light per CU
  const int bh = rank & 31;
  const int qt = 31 - (rank >> 5);                  // rank 0 = heaviest
  const int qb0 = qt * 64;
  const int tid = threadIdx.x, lane = tid & 63, wq = tid >> 6;
  const int g = lane >> 4, l15 = lane & 15;

  const bfbits* Qp = Qb + ((size_t)bh * T_ + qb0 + wq * 32) * DH_;
  const bfbits* Kp = Kb + (size_t)bh * T_ * DH_;
  const bfbits* Vp = Vt + (size_t)bh * DH_ * T_;

  // Q fragments: qi in {0,1} -> rows qb0+wq*32+qi*16+l15, two dh halves
  s16x8 qf[2][2];
  #pragma unroll
  for (int qi = 0; qi < 2; ++qi) {
    qf[qi][0] = *(const s16x8*)(Qp + (qi * 16 + l15) * DH_ + g * 8);
    qf[qi][1] = *(const s16x8*)(Qp + (qi * 16 + l15) * DH_ + 32 + g * 8);
  }

  f32x4 o[2][4] = {};
  float mrun[2] = {-INFINITY, -INFINITY};
  float lrun[2] = {0.f, 0.f};

  const int nk = qt + 1;                    // k-tiles for this block

  // stage tile (k0) into parity p. LDS chunk c holds global chunk c^(row&7)
  // (XOR swizzle applied on the SOURCE address; LDS dest stays linear).
  auto stage = [&](int k0, int p) {
    #pragma unroll
    for (int ii = 0; ii < 4; ++ii) {
      const int cb = ii * 128 + wq * 64;      // wave-uniform chunk base
      const int c = cb + lane;                // 0..511
      const int row = c >> 3;
      const int sc = ((c & 7) ^ (row & 7)) * 8;   // swizzled source elem offset
      gload16(Kp + (size_t)(k0 + row) * DH_ + sc, (char*)(&Kl[p][0]) + cb * 16);
      gload16(Vp + (size_t)row * T_ + (k0 + sc),  (char*)(&Vl[p][0]) + cb * 16);
    }
  };

  stage(0, 0);
  __syncthreads();

  for (int t = 0; t < nk; ++t) {
    const int p = t & 1;
    if (t + 1 < nk) stage((t + 1) << 6, p ^ 1);
    const int k0 = t << 6;
    {
      // ---- QK^T: S^T tile [64 k][16 q] per q-tile ----
      f32x4 st[2][4];
      #pragma unroll
      for (int kt = 0; kt < 4; ++kt) {
        const int krow = kt * 16 + l15;
        const int rs = krow & 7;
        const s16x8 ka  = *(const s16x8*)&Kl[p][krow * 64 + ((0 + g) ^ rs) * 8];
        const s16x8 kb2 = *(const s16x8*)&Kl[p][krow * 64 + ((4 + g) ^ rs) * 8];
        #pragma unroll
        for (int qi = 0; qi < 2; ++qi) {
          f32x4 z = {0.f, 0.f, 0.f, 0.f};
          z = __builtin_amdgcn_mfma_f32_16x16x32_bf16(ka,  qf[qi][0], z, 0, 0, 0);
          z = __builtin_amdgcn_mfma_f32_16x16x32_bf16(kb2, qf[qi][1], z, 0, 0, 0);
          st[qi][kt] = z;
        }
      }
      // ---- online softmax (exp2 domain; lane-local in k; q = l15) ----
      s16x8 pf[2][2];
      #pragma unroll
      for (int qi = 0; qi < 2; ++qi) {
        const int qrow = qb0 + wq * 32 + qi * 16 + l15;
        if (k0 + 63 > qrow) {               // causal mask on diagonal tiles
          #pragma unroll
          for (int kt = 0; kt < 4; ++kt)
            #pragma unroll
            for (int r = 0; r < 4; ++r)
              if (k0 + kt * 16 + g * 4 + r > qrow) st[qi][kt][r] = -1e9f;
        }
        f32x4 mv0, mv1;
        #pragma unroll
        for (int r = 0; r < 4; ++r) {
          mv0[r] = fmaxf(st[qi][0][r], st[qi][1][r]);
          mv1[r] = fmaxf(st[qi][2][r], st[qi][3][r]);
        }
        float mx = fmaxf(fmaxf(fmaxf(mv0[0], mv0[1]), fmaxf(mv0[2], mv0[3])),
                         fmaxf(fmaxf(mv1[0], mv1[1]), fmaxf(mv1[2], mv1[3])));
        mx = fmaxf(mx, __shfl_xor(mx, 16));
        mx = fmaxf(mx, __shfl_xor(mx, 32));
        const bool need = __any(mx > mrun[qi] + 8.f) != 0;   // defer-max
        const float mnew = need ? fmaxf(mrun[qi], mx) : mrun[qi];
        float sum = 0.f;
        #pragma unroll
        for (int kt = 0; kt < 4; ++kt)
          #pragma unroll
          for (int r = 0; r < 4; ++r) {
            const float e = vexp2(st[qi][kt][r] - mnew);
            st[qi][kt][r] = e;
            sum += e;
          }
        sum += __shfl_xor(sum, 16);
        sum += __shfl_xor(sum, 32);
        if (need) {
          const float alpha = vexp2(mrun[qi] - mnew);
          mrun[qi] = mnew;
          lrun[qi] = lrun[qi] * alpha + sum;
          #pragma unroll
          for (int dt = 0; dt < 4; ++dt) {
            o[qi][dt][0] *= alpha; o[qi][dt][1] *= alpha;
            o[qi][dt][2] *= alpha; o[qi][dt][3] *= alpha;
          }
        } else {
          lrun[qi] += sum;
        }
        #pragma unroll
        for (int ks = 0; ks < 2; ++ks) {
          uint4 w;
          w.x = pkbf(st[qi][2 * ks][0],     st[qi][2 * ks][1]);
          w.y = pkbf(st[qi][2 * ks][2],     st[qi][2 * ks][3]);
          w.z = pkbf(st[qi][2 * ks + 1][0], st[qi][2 * ks + 1][1]);
          w.w = pkbf(st[qi][2 * ks + 1][2], st[qi][2 * ks + 1][3]);
          pf[qi][ks] = __builtin_bit_cast(s16x8, w);
        }
      }
      // ---- PV: O^T += V^T * P^T (k-bijection matches pf layout) ----
      #pragma unroll
      for (int dt = 0; dt < 4; ++dt) {
        const int vrow = dt * 16 + l15;
        const int rs = vrow & 7;
        #pragma unroll
        for (int ks = 0; ks < 2; ++ks) {
          const u16x4 vlo = *(const u16x4*)&Vl[p][vrow * 64 + ((ks * 4 + 0 + (g >> 1)) ^ rs) * 8 + (g & 1) * 4];
          const u16x4 vhi = *(const u16x4*)&Vl[p][vrow * 64 + ((ks * 4 + 2 + (g >> 1)) ^ rs) * 8 + (g & 1) * 4];
          s16x8 vf;
          vf[0] = (short)vlo[0]; vf[1] = (short)vlo[1]; vf[2] = (short)vlo[2]; vf[3] = (short)vlo[3];
          vf[4] = (short)vhi[0]; vf[5] = (short)vhi[1]; vf[6] = (short)vhi[2]; vf[7] = (short)vhi[3];
          o[0][dt] = __builtin_amdgcn_mfma_f32_16x16x32_bf16(vf, pf[0][ks], o[0][dt], 0, 0, 0);
          o[1][dt] = __builtin_amdgcn_mfma_f32_16x16x32_bf16(vf, pf[1][ks], o[1][dt], 0, 0, 0);
        }
      }
    }
    __syncthreads();
  }

  const int b = bh >> 4, hh = bh & 15;
  #pragma unroll
  for (int qi = 0; qi < 2; ++qi) {
    const float inv = 1.0f / lrun[qi];
    bfbits* dst = AO + ((size_t)b * T_ + qb0 + wq * 32 + qi * 16 + l15) * D_ + hh * DH_;
    #pragma unroll
    for (int dt = 0; dt < 4; ++dt)
      #pragma unroll
      for (int r = 0; r < 4; ++r)
        dst[dt * 16 + g * 4 + r] = f2bf(o[qi][dt][r] * inv);
  }
}

// ---------- pooling / commit / center / final ----------
__global__ __launch_bounds__(256)
void pool_part(const float* __restrict__ x2, float* __restrict__ part) {
  const int s = blockIdx.x, b = blockIdx.y, tid = threadIdx.x;
  const float* base = x2 + ((size_t)b * T_ + s * 128) * D_ + tid * 4;
  float ax = 0, ay = 0, az = 0, aw = 0;
  for (int t = 0; t < 128; ++t) {
    float4 v = *(const float4*)(base + (size_t)t * D_);
    ax += v.x; ay += v.y; az += v.z; aw += v.w;
  }
  float4 ov; ov.x = ax; ov.y = ay; ov.z = az; ov.w = aw;
  *(float4*)(part + (size_t)(b * 16 + s) * D_ + tid * 4) = ov;
}

__global__ __launch_bounds__(256)
void pool_fin(const float* __restrict__ part, float* __restrict__ pool) {
  const int idx = blockIdx.x * 256 + threadIdx.x; // 0..2047
  const int b = idx >> 10, d = idx & 1023;
  float s = 0.f;
  for (int i = 0; i < 16; ++i) s += part[(size_t)(b * 16 + i) * D_ + d];
  pool[idx] = s * (1.0f / 2048.0f);
}

__global__ __launch_bounds__(256)
void commit_kernel(const float* __restrict__ pool, const float* __restrict__ cw,
                   const float* __restrict__ cb0, float* __restrict__ cmt,
                   float* __restrict__ out_cmt) {
  const int b = blockIdx.x, tid = threadIdx.x;
  float4 p = *(const float4*)(pool + b * 1024 + tid * 4);
  float4 w = *(const float4*)(cw + tid * 4);
  float s = p.x * w.x + p.y * w.y + p.z * w.z + p.w * w.w;
  #pragma unroll
  for (int o = 32; o > 0; o >>= 1) s += __shfl_xor(s, o);
  __shared__ float ls[4];
  if ((tid & 63) == 0) ls[tid >> 6] = s;
  __syncthreads();
  if (tid == 0) {
    const float t = ls[0] + ls[1] + ls[2] + ls[3] + cb0[0];
    const float v = 1.0f / (1.0f + expf(-t));
    cmt[b] = v; out_cmt[b] = v;
  }
}

__global__ __launch_bounds__(256)
void center_kernel(const float* __restrict__ pool, const float* __restrict__ cpw,
                   const float* __restrict__ cpb, float* __restrict__ outc) {
  const int idx = blockIdx.x * 256 + threadIdx.x; // 0..2047
  const int b = idx >> 10, c = idx & 1023;
  const float* pb = pool + b * 1024;
  float s = 0.f;
  for (int d = 0; d < 1024; ++d) s += pb[d] * cpw[(size_t)d * 1024 + c];
  outc[idx] = tanhf(s + cpb[c]);
}

__global__ __launch_bounds__(256)
void final_kernel(const float* __restrict__ x2, const float* __restrict__ ff,
                  const float* __restrict__ gate, const float* __restrict__ cmt,
                  float* __restrict__ outx) {
  const size_t i = (size_t)blockIdx.x * 256 + threadIdx.x; // * 4 elements
  const int m = (int)(i >> 8);
  const int b = m >> 11;
  const float k = cmt[b] * gate[m];
  float4 xv = *(const float4*)(x2 + i * 4);
  float4 fv = *(const float4*)(ff + i * 4);
  float4 ov;
  ov.x = xv.x + k * fv.x; ov.y = xv.y + k * fv.y;
  ov.z = xv.z + k * fv.z; ov.w = xv.w + k * fv.w;
  *(float4*)(outx + i * 4) = ov;
}

// ---------------- host launcher ----------------
extern "C" void kernel_launch(void* const* d_in, const int* in_sizes, int n_in,
                              void* d_out, int out_size, void* d_ws, size_t ws_size,
                              hipStream_t stream) {
  (void)in_sizes; (void)n_in; (void)out_size; (void)ws_size;
  const float* x       = (const float*)d_in[0];
  const float* cfa     = (const float*)d_in[1];
  const float* gate_w  = (const float*)d_in[3];
  const float* gate_b  = (const float*)d_in[4];
  const float* cb_w    = (const float*)d_in[5];
  const float* nf_g    = (const float*)d_in[6];
  const float* nf_b    = (const float*)d_in[7];
  const float* wq      = (const float*)d_in[8];
  const float* wk      = (const float*)d_in[9];
  const float* wv      = (const float*)d_in[10];
  const float* wo      = (const float*)d_in[11];
  const float* phase   = (const float*)d_in[12];
  const float* nb_g    = (const float*)d_in[13];
  const float* nb_b    = (const float*)d_in[14];
  const float* up_w    = (const float*)d_in[15];
  const float* up_b    = (const float*)d_in[16];
  const float* dn_w    = (const float*)d_in[17];
  const float* dn_b    = (const float*)d_in[18];
  const float* cmt_w   = (const float*)d_in[19];
  const float* cmt_b   = (const float*)d_in[20];
  const float* cproj_w = (const float*)d_in[21];
  const float* cproj_b = (const float*)d_in[22];
  const float* bcast_w = (const float*)d_in[23];
  const float* bcast_b = (const float*)d_in[24];

  char* ws = (char*)d_ws;
  float*  x1     = (float*)(ws + OFF_X1);
  float*  ff     = (float*)(ws + OFF_X1);     // alias: x1 dead after WO
  bfbits* h      = (bfbits*)(ws + OFF_H);
  bfbits* h2     = (bfbits*)(ws + OFF_H);     // alias: h dead after QKV
  bfbits* qb     = (bfbits*)(ws + OFF_Q);
  bfbits* kb     = (bfbits*)(ws + OFF_K);
  bfbits* vt     = (bfbits*)(ws + OFF_VT);
  bfbits* ffmid  = (bfbits*)(ws + OFF_Q);     // alias: Q/K dead after attention
  bfbits* ao     = (bfbits*)(ws + OFF_AO);
  float*  x2     = (float*)(ws + OFF_X2);
  bfbits* wqkv_t = (bfbits*)(ws + OFF_WQKV);
  bfbits* wo_t   = (bfbits*)(ws + OFF_WO);
  bfbits* wup_t  = (bfbits*)(ws + OFF_WUP);
  bfbits* wdn_t  = (bfbits*)(ws + OFF_WDN);
  float*  bvec   = (float*)(ws + OFF_BVEC);
  float*  cbv    = (float*)(ws + OFF_CBV);
  float*  gate   = (float*)(ws + OFF_GATE);
  float*  part   = (float*)(ws + OFF_PART);
  float*  pool   = (float*)(ws + OFF_POOL);
  float*  cmt    = (float*)(ws + OFF_CMT);

  float* outx   = (float*)d_out;
  float* outc   = outx + NELEM_X;          // center [B][DC]
  float* outg   = outc + B_ * DC_;         // gate [B][T]
  float* outcmt = outg + B_ * T_;          // commit [B]

  // weight prep (B^T bf16)
  transpose_w<<<dim3(32, 32), 256, 0, stream>>>(wq, wqkv_t,                1024, 1024, 1024, 1024);
  transpose_w<<<dim3(32, 32), 256, 0, stream>>>(wk, wqkv_t + 1024 * 1024,  1024, 1024, 1024, 1024);
  transpose_w<<<dim3(32, 32), 256, 0, stream>>>(wv, wqkv_t + 2048 * 1024,  1024, 1024, 1024, 1024);
  transpose_w<<<dim3(32, 32), 256, 0, stream>>>(wo, wo_t,                  1024, 1024, 1024, 1024);
  transpose_w<<<dim3(32, 52), 256, 0, stream>>>(up_w, wup_t,               1024, DFF_, 1024, DFFP_);
  transpose_w<<<dim3(52, 32), 256, 0, stream>>>(dn_w, wdn_t,               DFF_, 1024, DFFP_, 1024);

  bvec_kernel<<<8, 256, 0, stream>>>(cfa, bcast_w, bcast_b, bvec);
  cb_kernel<<<B_, 256, 0, stream>>>(cfa, cb_w, cbv);

  ln1_kernel<<<MTOT, 256, 0, stream>>>(x, bvec, cbv, gate_w, gate_b, nf_g, nf_b,
                                       x1, h, gate, outg);

  gemm_bt<0><<<dim3(24, 32), 256, 0, stream>>>(h, 1024, wqkv_t, 1024, 1024,
                                               gate, phase, nullptr, qb, kb, vt);

  attn_kernel<<<1024, 128, 0, stream>>>(qb, kb, vt, ao);

  gemm_bt<1><<<dim3(8, 32), 256, 0, stream>>>(ao, 1024, wo_t, 1024, 1024,
                                              gate, x1, x2, nullptr, nullptr, nullptr);

  ln2_kernel<<<MTOT, 256, 0, stream>>>(x2, nb_g, nb_b, h2);

  gemm_bt<2><<<dim3(13, 32), 256, 0, stream>>>(h2, 1024, wup_t, 1024, 1024,
                                               up_b, nullptr, nullptr, ffmid, nullptr, nullptr);

  gemm_bt<3><<<dim3(8, 32), 256, 0, stream>>>(ffmid, DFFP_, wdn_t, DFFP_, DFFP_,
                                              dn_b, nullptr, ff, nullptr, nullptr, nullptr);

  pool_part<<<dim3(16, B_), 256, 0, stream>>>(x2, part);
  pool_fin<<<8, 256, 0, stream>>>(part, pool);
  commit_kernel<<<B_, 256, 0, stream>>>(pool, cmt_w, cmt_b, cmt, outcmt);
  center_kernel<<<8, 256, 0, stream>>>(pool, cproj_w, cproj_b, outc);

  final_kernel<<<4096, 256, 0, stream>>>(x2, ff, gate, cmt, outx);
}

// Round 4
// 268.710 us; speedup vs baseline: 2.2151x; 1.1923x over previous
//
#include <hip/hip_runtime.h>
#include <math.h>

// ---- problem constants ----
#define B_   2
#define T_   2048
#define D_   1024
#define H_   16
#define DH_  64
#define DC_  1024
#define DFF_ 1656
#define DFFP_ 1664
#define MTOT 4096          // B_*T_
#define NELEM_X 4194304ull // B*T*D

typedef short s16x8 __attribute__((ext_vector_type(8)));
typedef unsigned short u16x4 __attribute__((ext_vector_type(4)));
typedef float f32x4 __attribute__((ext_vector_type(4)));
typedef unsigned short bfbits;

__device__ __forceinline__ bfbits f2bf(float f) {
  unsigned int u = __builtin_bit_cast(unsigned int, f);
  u += 0x7fffu + ((u >> 16) & 1u);          // RNE
  return (bfbits)(u >> 16);
}

__device__ __forceinline__ float vexp2(float x) {   // 2^x via HW transcendental
  float r;
  asm("v_exp_f32 %0, %1" : "=v"(r) : "v"(x));
  return r;
}
__device__ __forceinline__ unsigned pkbf(float lo, float hi) { // 2xbf16 pack, RNE
  unsigned r;
  asm("v_cvt_pk_bf16_f32 %0, %1, %2" : "=v"(r) : "v"(lo), "v"(hi));
  return r;
}

__device__ __forceinline__ void gload16(const void* g, void* l) {
  __builtin_amdgcn_global_load_lds(
      (__attribute__((address_space(1))) void*)g,
      (__attribute__((address_space(3))) void*)l, 16, 0, 0);
}

// ---------- workspace offsets (bytes) ----------
constexpr size_t OFF_X1   = 0;                                  // f32 x1
constexpr size_t OFF_H    = OFF_X1 + 4ull*NELEM_X;              // bf16 h ; later h2
constexpr size_t OFF_Q    = OFF_H  + 2ull*NELEM_X;              // bf16 Q [BH][T][64] ; later ffmid
constexpr size_t OFF_K    = OFF_Q  + 2ull*NELEM_X;              // bf16 K [BH][T][64]
constexpr size_t OFF_VT   = OFF_K  + 2ull*NELEM_X;              // bf16 V^T [BH][64][T]
constexpr size_t OFF_AO   = OFF_VT + 2ull*NELEM_X;              // bf16 attn out [M][D]
constexpr size_t OFF_X2   = OFF_AO + 2ull*NELEM_X;              // f32 x2
constexpr size_t OFF_WQKV = OFF_X2 + 4ull*NELEM_X;              // bf16 [3072][1024]
constexpr size_t OFF_WO   = OFF_WQKV + 3072ull*1024*2;          // bf16 [1024][1024]
constexpr size_t OFF_WUP  = OFF_WO   + 1024ull*1024*2;          // bf16 [1664][1024]
constexpr size_t OFF_WDN  = OFF_WUP  + 1664ull*1024*2;          // bf16 [1024][1664]
constexpr size_t OFF_BVEC = OFF_WDN  + 1024ull*1664*2;          // f32 [B][D]
constexpr size_t OFF_CBV  = OFF_BVEC + 2048ull*4;               // f32 [B]
constexpr size_t OFF_GATE = OFF_CBV  + 256;                     // f32 [M]
constexpr size_t OFF_PART = OFF_GATE + 4096ull*4;               // f32 [32][1024]
constexpr size_t OFF_POOL = OFF_PART + 32ull*1024*4;            // f32 [B][D]
constexpr size_t OFF_CMT  = OFF_POOL + 2048ull*4;               // f32 [B]

// ---------- transpose f32 [R][C] -> bf16 [Npad][Rpad], dst[n][k] = (k<R && n<C) ? src[k][n] : 0
__global__ __launch_bounds__(256)
void transpose_w(const float* __restrict__ src, bfbits* __restrict__ dst,
                 int R, int C, int Rpad, int Npad) {
  __shared__ float tile[32][33];
  const int kb = blockIdx.x * 32, nb = blockIdx.y * 32;
  const int tx = threadIdx.x & 31, ty = threadIdx.x >> 5;
  for (int i = ty; i < 32; i += 8) {
    const int k = kb + i, n = nb + tx;
    tile[i][tx] = (k < R && n < C) ? src[(size_t)k * C + n] : 0.f;
  }
  __syncthreads();
  for (int i = ty; i < 32; i += 8) {
    const int n = nb + i, k = kb + tx;
    if (n < Npad && k < Rpad) dst[(size_t)n * Rpad + k] = f2bf(tile[tx][i]);
  }
}

// ---------- GEMV: out[b][d] = f(vec[b]. @ w[.][d] + bias[d]); w is [1024][1024]
// grid (32, B_): 32 d-columns per block; 8-way c-split + LDS reduce.
__global__ __launch_bounds__(256)
void gemv_t(const float* __restrict__ v, const float* __restrict__ w,
            const float* __restrict__ bias, float* __restrict__ out,
            int tanh_mode) {
  const int b = blockIdx.y;
  const int dl = threadIdx.x & 31, cl = threadIdx.x >> 5;
  const int d = blockIdx.x * 32 + dl;
  const float* vb = v + b * 1024;
  float s = 0.f;
  #pragma unroll 4
  for (int c = cl; c < 1024; c += 8)
    s += vb[c] * w[(size_t)c * 1024 + d];
  __shared__ float red[8][32];
  red[cl][dl] = s;
  __syncthreads();
  if (threadIdx.x < 32) {
    float t = 0.f;
    #pragma unroll
    for (int i = 0; i < 8; ++i) t += red[i][threadIdx.x];
    const int dd = blockIdx.x * 32 + threadIdx.x;
    t += bias[dd];
    out[b * 1024 + dd] = tanh_mode ? tanhf(t) : t;
  }
}

__global__ __launch_bounds__(256)
void cb_kernel(const float* __restrict__ cfa, const float* __restrict__ cbw,
               float* __restrict__ cbv) {
  const int b = blockIdx.x, tid = threadIdx.x;
  float4 a = *(const float4*)(cfa + b * 1024 + tid * 4);
  float4 w = *(const float4*)(cbw + tid * 4);
  float s = a.x * w.x + a.y * w.y + a.z * w.z + a.w * w.w;
  #pragma unroll
  for (int o = 32; o > 0; o >>= 1) s += __shfl_xor(s, o);
  __shared__ float ls[4];
  if ((tid & 63) == 0) ls[tid >> 6] = s;
  __syncthreads();
  if (tid == 0) cbv[b] = ls[0] + ls[1] + ls[2] + ls[3];
}

__device__ __forceinline__ void blockreduce3(float& a, float& b, float& c) {
  #pragma unroll
  for (int o = 32; o > 0; o >>= 1) {
    a += __shfl_xor(a, o);
    b += __shfl_xor(b, o);
    c += __shfl_xor(c, o);
  }
  __shared__ float ls[3][4];
  const int lane = threadIdx.x & 63, w = threadIdx.x >> 6;
  if (lane == 0) { ls[0][w] = a; ls[1][w] = b; ls[2][w] = c; }
  __syncthreads();
  a = ls[0][0] + ls[0][1] + ls[0][2] + ls[0][3];
  b = ls[1][0] + ls[1][1] + ls[1][2] + ls[1][3];
  c = ls[2][0] + ls[2][1] + ls[2][2] + ls[2][3];
}

// ---------- fused: x1 = x + bvec ; gate ; LN(x1) -> h (bf16)
__global__ __launch_bounds__(256)
void ln1_kernel(const float* __restrict__ x, const float* __restrict__ bvec,
                const float* __restrict__ cbv, const float* __restrict__ gw,
                const float* __restrict__ gb, const float* __restrict__ nfg,
                const float* __restrict__ nfb, float* __restrict__ x1,
                bfbits* __restrict__ h, float* __restrict__ gate_ws,
                float* __restrict__ gate_out) {
  const int m = blockIdx.x, tid = threadIdx.x, b = m >> 11;
  const size_t ro = (size_t)m * D_ + tid * 4;
  float4 xv = *(const float4*)(x + ro);
  float4 bv = *(const float4*)(bvec + b * D_ + tid * 4);
  float4 v;
  v.x = xv.x + bv.x; v.y = xv.y + bv.y; v.z = xv.z + bv.z; v.w = xv.w + bv.w;
  float4 g4 = *(const float4*)(gw + tid * 4);
  float s  = v.x + v.y + v.z + v.w;
  float s2 = v.x*v.x + v.y*v.y + v.z*v.z + v.w*v.w;
  float dg = v.x*g4.x + v.y*g4.y + v.z*g4.z + v.w*g4.w;
  blockreduce3(s, s2, dg);
  const float mean = s * (1.0f/1024.0f);
  const float var  = s2 * (1.0f/1024.0f) - mean*mean;
  const float rstd = rsqrtf(var + 1e-5f);
  if (tid == 0) {
    const float logits = dg + gb[0] + cbv[b];
    const float prob = 1.0f / (1.0f + expf(-logits));
    const float hard = prob > 0.5f ? 1.0f : 0.0f;
    const float gv = (hard - prob) + prob;
    gate_ws[m] = gv; gate_out[m] = gv;
  }
  *(float4*)(x1 + ro) = v;
  float4 gg = *(const float4*)(nfg + tid * 4);
  float4 b2 = *(const float4*)(nfb + tid * 4);
  u16x4 hv;
  hv[0] = f2bf((v.x - mean) * rstd * gg.x + b2.x);
  hv[1] = f2bf((v.y - mean) * rstd * gg.y + b2.y);
  hv[2] = f2bf((v.z - mean) * rstd * gg.z + b2.z);
  hv[3] = f2bf((v.w - mean) * rstd * gg.w + b2.w);
  *(u16x4*)(h + ro) = hv;
}

__global__ __launch_bounds__(256)
void ln2_kernel(const float* __restrict__ x2, const float* __restrict__ gptr,
                const float* __restrict__ bptr, bfbits* __restrict__ h2) {
  const int m = blockIdx.x, tid = threadIdx.x;
  const size_t ro = (size_t)m * D_ + tid * 4;
  float4 v = *(const float4*)(x2 + ro);
  float s  = v.x + v.y + v.z + v.w;
  float s2 = v.x*v.x + v.y*v.y + v.z*v.z + v.w*v.w;
  float d0 = 0.f;
  blockreduce3(s, s2, d0);
  const float mean = s * (1.0f/1024.0f);
  const float var  = s2 * (1.0f/1024.0f) - mean*mean;
  const float rstd = rsqrtf(var + 1e-5f);
  float4 gg = *(const float4*)(gptr + tid * 4);
  float4 b2 = *(const float4*)(bptr + tid * 4);
  u16x4 hv;
  hv[0] = f2bf((v.x - mean) * rstd * gg.x + b2.x);
  hv[1] = f2bf((v.y - mean) * rstd * gg.y + b2.y);
  hv[2] = f2bf((v.z - mean) * rstd * gg.z + b2.z);
  hv[3] = f2bf((v.w - mean) * rstd * gg.w + b2.w);
  *(u16x4*)(h2 + ro) = hv;
}

// ---------- GEMM: C[M][N] = A[M][K](bf16,row-major) * Bt[N][K](bf16), fused epilogues
// BM in {128, 64}; BN fixed 128; 4 waves, wave tile (BM/2) x 64.
// EPI 0: QKV (rope+gate, Q scaled (1/8)*log2e; V -> V^T)   [BM=128]
// EPI 1: WO (x2 = x1 + C*gate)                              [BM=64]
// EPI 2: UP (gelu(C+up_b) -> bf16, ldc=1664)                [BM=64]
// EPI 3: DN fused final (outx = x2 + cmt*gate*(C+dn_b))     [BM=64]
template <int EPI, int BM>
__global__ void __launch_bounds__(256, 2)
gemm_bt(const bfbits* __restrict__ A, int lda,
        const bfbits* __restrict__ Bt, int ldb, int K,
        const float* __restrict__ p0, const float* __restrict__ p1,
        const float* __restrict__ p2,
        float* __restrict__ fo0, const float* __restrict__ fo1,
        bfbits* __restrict__ bo0, bfbits* __restrict__ bo1,
        bfbits* __restrict__ bo2) {
  constexpr int MI = BM / 32;               // m-fragments per wave
  __shared__ bfbits Asl[BM * 32];
  __shared__ bfbits Bsl[128 * 32];
  const int tid = threadIdx.x;
  const int lane = tid & 63, wave = tid >> 6;
  const int g = lane >> 4, l15 = lane & 15;
  const int wr = wave >> 1, wc = wave & 1;
  const int m0 = blockIdx.y * BM, n0 = blockIdx.x * 128;

  f32x4 acc[MI][4] = {};

  for (int k0 = 0; k0 < K; k0 += 32) {
    #pragma unroll
    for (int c = wave; c < BM / 16; c += 4) {
      const int e = c * 512 + lane * 8;
      const int row = e >> 5, ko = e & 31;
      gload16(A + (size_t)(m0 + row) * lda + (k0 + ko), (char*)Asl + c * 1024);
    }
    #pragma unroll
    for (int c = wave; c < 8; c += 4) {
      const int e = c * 512 + lane * 8;
      const int row = e >> 5, ko = e & 31;
      gload16(Bt + (size_t)(n0 + row) * ldb + (k0 + ko), (char*)Bsl + c * 1024);
    }
    __syncthreads();
    s16x8 af[MI], bfr[4];
    #pragma unroll
    for (int i = 0; i < MI; ++i)
      af[i] = *(const s16x8*)&Asl[(wr * (MI * 16) + i * 16 + l15) * 32 + g * 8];
    #pragma unroll
    for (int i = 0; i < 4; ++i)
      bfr[i] = *(const s16x8*)&Bsl[(wc * 64 + i * 16 + l15) * 32 + g * 8];
    #pragma unroll
    for (int i = 0; i < MI; ++i)
      #pragma unroll
      for (int j = 0; j < 4; ++j)
        acc[i][j] = __builtin_amdgcn_mfma_f32_16x16x32_bf16(af[i], bfr[j], acc[i][j], 0, 0, 0);
    __syncthreads();
  }

  const int b = m0 >> 11;
  const int trow0 = (m0 & 2047) + wr * (MI * 16);

  if constexpr (EPI == 0) {
    const float* gate = p0;
    const float* phase = p1;
    const int ncol0 = n0 + wc * 64;           // 64-aligned wave column base
    const int section = ncol0 >> 10;          // 0=Q 1=K 2=V
    const int hh = (ncol0 & 1023) >> 6;
    if (section == 2) {
      bfbits* vt = bo2;
      const size_t vhead = (size_t)(b * H_ + hh) * DH_ * T_;
      #pragma unroll
      for (int mi = 0; mi < MI; ++mi) {
        const int tb = trow0 + mi * 16 + g * 4;
        #pragma unroll
        for (int ni = 0; ni < 4; ++ni) {
          const int dh = ni * 16 + l15;
          #pragma unroll
          for (int r = 0; r < 4; ++r)
            vt[vhead + (size_t)dh * T_ + (tb + r)] = f2bf(acc[mi][ni][r]);
        }
      }
    } else {
      const float cc = cosf(phase[hh]);
      const float ssn = sinf(phase[hh]);
      // Q side carries 1/sqrt(DH) AND log2(e): scores land in exp2 domain.
      const float qs = (section == 0) ? 0.125f * 1.44269504088896341f : 1.0f;
      bfbits* dst = (section == 0) ? bo0 : bo1;
      const size_t head = (size_t)(b * H_ + hh) * T_ * DH_;
      #pragma unroll
      for (int mi = 0; mi < MI; ++mi) {
        const int tb = trow0 + mi * 16 + g * 4;
        float gv[4];
        #pragma unroll
        for (int r = 0; r < 4; ++r) gv[r] = gate[(size_t)b * T_ + tb + r] * qs;
        #pragma unroll
        for (int ni = 0; ni < 2; ++ni) {
          const int dh = ni * 16 + l15;
          #pragma unroll
          for (int r = 0; r < 4; ++r) {
            const float re = acc[mi][ni][r];
            const float im = acc[mi][ni + 2][r];
            const size_t idx = head + (size_t)(tb + r) * DH_ + dh;
            dst[idx]      = f2bf((re * cc - im * ssn) * gv[r]);
            dst[idx + 32] = f2bf((re * ssn + im * cc) * gv[r]);
          }
        }
      }
    }
  } else if constexpr (EPI == 1) {
    const float* gate = p0;
    const float* x1 = fo1;
    float* x2 = fo0;
    #pragma unroll
    for (int mi = 0; mi < MI; ++mi) {
      const int m = m0 + wr * (MI * 16) + mi * 16 + g * 4;
      float gv[4];
      #pragma unroll
      for (int r = 0; r < 4; ++r) gv[r] = gate[m + r];
      #pragma unroll
      for (int ni = 0; ni < 4; ++ni) {
        const int n = n0 + wc * 64 + ni * 16 + l15;
        #pragma unroll
        for (int r = 0; r < 4; ++r) {
          const size_t idx = (size_t)(m + r) * D_ + n;
          x2[idx] = x1[idx] + acc[mi][ni][r] * gv[r];
        }
      }
    }
  } else if constexpr (EPI == 2) {
    const float* upb = p0;
    bfbits* outm = bo0;
    #pragma unroll
    for (int mi = 0; mi < MI; ++mi) {
      const int m = m0 + wr * (MI * 16) + mi * 16 + g * 4;
      #pragma unroll
      for (int ni = 0; ni < 4; ++ni) {
        const int n = n0 + wc * 64 + ni * 16 + l15;
        const float bb = upb[n < DFF_ ? n : DFF_ - 1];
        #pragma unroll
        for (int r = 0; r < 4; ++r) {
          float v = acc[mi][ni][r] + bb;
          v = 0.5f * v * (1.0f + erff(v * 0.70710678118654752f));
          outm[(size_t)(m + r) * DFFP_ + n] = f2bf(v);
        }
      }
    }
  } else {
    const float* dnb = p0;
    const float* gate = p1;
    const float* cmt = p2;
    const float* x2 = fo1;
    float* outx = fo0;
    const float cb = cmt[b];
    #pragma unroll
    for (int mi = 0; mi < MI; ++mi) {
      const int m = m0 + wr * (MI * 16) + mi * 16 + g * 4;
      float kv[4];
      #pragma unroll
      for (int r = 0; r < 4; ++r) kv[r] = cb * gate[m + r];
      #pragma unroll
      for (int ni = 0; ni < 4; ++ni) {
        const int n = n0 + wc * 64 + ni * 16 + l15;
        const float bb = dnb[n];
        #pragma unroll
        for (int r = 0; r < 4; ++r) {
          const size_t idx = (size_t)(m + r) * D_ + n;
          outx[idx] = x2[idx] + kv[r] * (acc[mi][ni][r] + bb);
        }
      }
    }
  }
}

// ---------- flash attention v4: 2 waves/block, 64 q-rows/block, KVBLK=64
// grid = 1024 blocks, boustrophedon qt mapping: the 4 blocks landing on each
// CU slot have k-tile counts summing to exactly 66 (= mean). All 1024 blocks
// co-resident (4 x 32KB LDS, 84 VGPR). Softmax in exp2 domain, defer-max,
// v_cvt_pk_bf16_f32 P-pack, setprio around MFMA clusters.
__global__ void __launch_bounds__(128, 2)
attn_kernel(const bfbits* __restrict__ Qb, const bfbits* __restrict__ Kb,
            const bfbits* __restrict__ Vt, bfbits* __restrict__ AO) {
  __shared__ bfbits Kl[2][64 * 64];
  __shared__ bfbits Vl[2][64 * 64];
  const int pid = blockIdx.x;                       // 0..1023
  const int bh = pid & 31;
  const int j = (pid >> 5) & 7;
  const int quarter = pid >> 8;
  const int qt = (quarter == 0) ? 31 - j
               : (quarter == 1) ? 16 + j
               : (quarter == 2) ? 15 - j
               : j;                                  // per-CU-slot sum = 66
  const int qb0 = qt * 64;
  const int tid = threadIdx.x, lane = tid & 63, wq = tid >> 6;
  const int g = lane >> 4, l15 = lane & 15;

  const bfbits* Qp = Qb + ((size_t)bh * T_ + qb0 + wq * 32) * DH_;
  const bfbits* Kp = Kb + (size_t)bh * T_ * DH_;
  const bfbits* Vp = Vt + (size_t)bh * DH_ * T_;

  // Q fragments: qi in {0,1} -> rows qb0+wq*32+qi*16+l15, two dh halves
  s16x8 qf[2][2];
  #pragma unroll
  for (int qi = 0; qi < 2; ++qi) {
    qf[qi][0] = *(const s16x8*)(Qp + (qi * 16 + l15) * DH_ + g * 8);
    qf[qi][1] = *(const s16x8*)(Qp + (qi * 16 + l15) * DH_ + 32 + g * 8);
  }

  f32x4 o[2][4] = {};
  float mrun[2] = {-INFINITY, -INFINITY};
  float lrun[2] = {0.f, 0.f};

  const int nk = qt + 1;                    // k-tiles for this block

  // stage tile (k0) into parity p. LDS chunk c holds global chunk c^(row&7)
  // (XOR swizzle applied on the SOURCE address; LDS dest stays linear).
  auto stage = [&](int k0, int p) {
    #pragma unroll
    for (int ii = 0; ii < 4; ++ii) {
      const int cb = ii * 128 + wq * 64;      // wave-uniform chunk base
      const int c = cb + lane;                // 0..511
      const int row = c >> 3;
      const int sc = ((c & 7) ^ (row & 7)) * 8;   // swizzled source elem offset
      gload16(Kp + (size_t)(k0 + row) * DH_ + sc, (char*)(&Kl[p][0]) + cb * 16);
      gload16(Vp + (size_t)row * T_ + (k0 + sc),  (char*)(&Vl[p][0]) + cb * 16);
    }
  };

  stage(0, 0);
  __syncthreads();

  for (int t = 0; t < nk; ++t) {
    const int p = t & 1;
    if (t + 1 < nk) stage((t + 1) << 6, p ^ 1);
    const int k0 = t << 6;
    {
      // ---- QK^T: S^T tile [64 k][16 q] per q-tile ----
      f32x4 st[2][4];
      __builtin_amdgcn_s_setprio(1);
      #pragma unroll
      for (int kt = 0; kt < 4; ++kt) {
        const int krow = kt * 16 + l15;
        const int rs = krow & 7;
        const s16x8 ka  = *(const s16x8*)&Kl[p][krow * 64 + ((0 + g) ^ rs) * 8];
        const s16x8 kb2 = *(const s16x8*)&Kl[p][krow * 64 + ((4 + g) ^ rs) * 8];
        #pragma unroll
        for (int qi = 0; qi < 2; ++qi) {
          f32x4 z = {0.f, 0.f, 0.f, 0.f};
          z = __builtin_amdgcn_mfma_f32_16x16x32_bf16(ka,  qf[qi][0], z, 0, 0, 0);
          z = __builtin_amdgcn_mfma_f32_16x16x32_bf16(kb2, qf[qi][1], z, 0, 0, 0);
          st[qi][kt] = z;
        }
      }
      __builtin_amdgcn_s_setprio(0);
      // ---- online softmax (exp2 domain; lane-local in k; q = l15) ----
      s16x8 pf[2][2];
      #pragma unroll
      for (int qi = 0; qi < 2; ++qi) {
        const int qrow = qb0 + wq * 32 + qi * 16 + l15;
        if (k0 + 63 > qrow) {               // causal mask on diagonal tiles
          #pragma unroll
          for (int kt = 0; kt < 4; ++kt)
            #pragma unroll
            for (int r = 0; r < 4; ++r)
              if (k0 + kt * 16 + g * 4 + r > qrow) st[qi][kt][r] = -1e9f;
        }
        f32x4 mv0, mv1;
        #pragma unroll
        for (int r = 0; r < 4; ++r) {
          mv0[r] = fmaxf(st[qi][0][r], st[qi][1][r]);
          mv1[r] = fmaxf(st[qi][2][r], st[qi][3][r]);
        }
        float mx = fmaxf(fmaxf(fmaxf(mv0[0], mv0[1]), fmaxf(mv0[2], mv0[3])),
                         fmaxf(fmaxf(mv1[0], mv1[1]), fmaxf(mv1[2], mv1[3])));
        mx = fmaxf(mx, __shfl_xor(mx, 16));
        mx = fmaxf(mx, __shfl_xor(mx, 32));
        const bool need = __any(mx > mrun[qi] + 8.f) != 0;   // defer-max
        const float mnew = need ? fmaxf(mrun[qi], mx) : mrun[qi];
        float sum = 0.f;
        #pragma unroll
        for (int kt = 0; kt < 4; ++kt)
          #pragma unroll
          for (int r = 0; r < 4; ++r) {
            const float e = vexp2(st[qi][kt][r] - mnew);
            st[qi][kt][r] = e;
            sum += e;
          }
        sum += __shfl_xor(sum, 16);
        sum += __shfl_xor(sum, 32);
        if (need) {
          const float alpha = vexp2(mrun[qi] - mnew);
          mrun[qi] = mnew;
          lrun[qi] = lrun[qi] * alpha + sum;
          #pragma unroll
          for (int dt = 0; dt < 4; ++dt) {
            o[qi][dt][0] *= alpha; o[qi][dt][1] *= alpha;
            o[qi][dt][2] *= alpha; o[qi][dt][3] *= alpha;
          }
        } else {
          lrun[qi] += sum;
        }
        #pragma unroll
        for (int ks = 0; ks < 2; ++ks) {
          uint4 w;
          w.x = pkbf(st[qi][2 * ks][0],     st[qi][2 * ks][1]);
          w.y = pkbf(st[qi][2 * ks][2],     st[qi][2 * ks][3]);
          w.z = pkbf(st[qi][2 * ks + 1][0], st[qi][2 * ks + 1][1]);
          w.w = pkbf(st[qi][2 * ks + 1][2], st[qi][2 * ks + 1][3]);
          pf[qi][ks] = __builtin_bit_cast(s16x8, w);
        }
      }
      // ---- PV: O^T += V^T * P^T (k-bijection matches pf layout) ----
      __builtin_amdgcn_s_setprio(1);
      #pragma unroll
      for (int dt = 0; dt < 4; ++dt) {
        const int vrow = dt * 16 + l15;
        const int rs = vrow & 7;
        #pragma unroll
        for (int ks = 0; ks < 2; ++ks) {
          const u16x4 vlo = *(const u16x4*)&Vl[p][vrow * 64 + ((ks * 4 + 0 + (g >> 1)) ^ rs) * 8 + (g & 1) * 4];
          const u16x4 vhi = *(const u16x4*)&Vl[p][vrow * 64 + ((ks * 4 + 2 + (g >> 1)) ^ rs) * 8 + (g & 1) * 4];
          s16x8 vf;
          vf[0] = (short)vlo[0]; vf[1] = (short)vlo[1]; vf[2] = (short)vlo[2]; vf[3] = (short)vlo[3];
          vf[4] = (short)vhi[0]; vf[5] = (short)vhi[1]; vf[6] = (short)vhi[2]; vf[7] = (short)vhi[3];
          o[0][dt] = __builtin_amdgcn_mfma_f32_16x16x32_bf16(vf, pf[0][ks], o[0][dt], 0, 0, 0);
          o[1][dt] = __builtin_amdgcn_mfma_f32_16x16x32_bf16(vf, pf[1][ks], o[1][dt], 0, 0, 0);
        }
      }
      __builtin_amdgcn_s_setprio(0);
    }
    __syncthreads();
  }

  const int b = bh >> 4, hh = bh & 15;
  #pragma unroll
  for (int qi = 0; qi < 2; ++qi) {
    const float inv = 1.0f / lrun[qi];
    bfbits* dst = AO + ((size_t)b * T_ + qb0 + wq * 32 + qi * 16 + l15) * D_ + hh * DH_;
    #pragma unroll
    for (int dt = 0; dt < 4; ++dt)
      #pragma unroll
      for (int r = 0; r < 4; ++r)
        dst[dt * 16 + g * 4 + r] = f2bf(o[qi][dt][r] * inv);
  }
}

// ---------- pooling / commit ----------
__global__ __launch_bounds__(256)
void pool_part(const float* __restrict__ x2, float* __restrict__ part) {
  const int s = blockIdx.x, b = blockIdx.y, tid = threadIdx.x;
  const float* base = x2 + ((size_t)b * T_ + s * 128) * D_ + tid * 4;
  float ax = 0, ay = 0, az = 0, aw = 0;
  for (int t = 0; t < 128; ++t) {
    float4 v = *(const float4*)(base + (size_t)t * D_);
    ax += v.x; ay += v.y; az += v.z; aw += v.w;
  }
  float4 ov; ov.x = ax; ov.y = ay; ov.z = az; ov.w = aw;
  *(float4*)(part + (size_t)(b * 16 + s) * D_ + tid * 4) = ov;
}

__global__ __launch_bounds__(256)
void pool_fin(const float* __restrict__ part, float* __restrict__ pool) {
  const int idx = blockIdx.x * 256 + threadIdx.x; // 0..2047
  const int b = idx >> 10, d = idx & 1023;
  float s = 0.f;
  for (int i = 0; i < 16; ++i) s += part[(size_t)(b * 16 + i) * D_ + d];
  pool[idx] = s * (1.0f / 2048.0f);
}

__global__ __launch_bounds__(256)
void commit_kernel(const float* __restrict__ pool, const float* __restrict__ cw,
                   const float* __restrict__ cb0, float* __restrict__ cmt,
                   float* __restrict__ out_cmt) {
  const int b = blockIdx.x, tid = threadIdx.x;
  float4 p = *(const float4*)(pool + b * 1024 + tid * 4);
  float4 w = *(const float4*)(cw + tid * 4);
  float s = p.x * w.x + p.y * w.y + p.z * w.z + p.w * w.w;
  #pragma unroll
  for (int o = 32; o > 0; o >>= 1) s += __shfl_xor(s, o);
  __shared__ float ls[4];
  if ((tid & 63) == 0) ls[tid >> 6] = s;
  __syncthreads();
  if (tid == 0) {
    const float t = ls[0] + ls[1] + ls[2] + ls[3] + cb0[0];
    const float v = 1.0f / (1.0f + expf(-t));
    cmt[b] = v; out_cmt[b] = v;
  }
}

// ---------------- host launcher ----------------
extern "C" void kernel_launch(void* const* d_in, const int* in_sizes, int n_in,
                              void* d_out, int out_size, void* d_ws, size_t ws_size,
                              hipStream_t stream) {
  (void)in_sizes; (void)n_in; (void)out_size; (void)ws_size;
  const float* x       = (const float*)d_in[0];
  const float* cfa     = (const float*)d_in[1];
  const float* gate_w  = (const float*)d_in[3];
  const float* gate_b  = (const float*)d_in[4];
  const float* cb_w    = (const float*)d_in[5];
  const float* nf_g    = (const float*)d_in[6];
  const float* nf_b    = (const float*)d_in[7];
  const float* wq      = (const float*)d_in[8];
  const float* wk      = (const float*)d_in[9];
  const float* wv      = (const float*)d_in[10];
  const float* wo      = (const float*)d_in[11];
  const float* phase   = (const float*)d_in[12];
  const float* nb_g    = (const float*)d_in[13];
  const float* nb_b    = (const float*)d_in[14];
  const float* up_w    = (const float*)d_in[15];
  const float* up_b    = (const float*)d_in[16];
  const float* dn_w    = (const float*)d_in[17];
  const float* dn_b    = (const float*)d_in[18];
  const float* cmt_w   = (const float*)d_in[19];
  const float* cmt_b   = (const float*)d_in[20];
  const float* cproj_w = (const float*)d_in[21];
  const float* cproj_b = (const float*)d_in[22];
  const float* bcast_w = (const float*)d_in[23];
  const float* bcast_b = (const float*)d_in[24];

  char* ws = (char*)d_ws;
  float*  x1     = (float*)(ws + OFF_X1);
  bfbits* h      = (bfbits*)(ws + OFF_H);
  bfbits* h2     = (bfbits*)(ws + OFF_H);     // alias: h dead after QKV
  bfbits* qb     = (bfbits*)(ws + OFF_Q);
  bfbits* kb     = (bfbits*)(ws + OFF_K);
  bfbits* vt     = (bfbits*)(ws + OFF_VT);
  bfbits* ffmid  = (bfbits*)(ws + OFF_Q);     // alias: Q/K dead after attention
  bfbits* ao     = (bfbits*)(ws + OFF_AO);
  float*  x2     = (float*)(ws + OFF_X2);
  bfbits* wqkv_t = (bfbits*)(ws + OFF_WQKV);
  bfbits* wo_t   = (bfbits*)(ws + OFF_WO);
  bfbits* wup_t  = (bfbits*)(ws + OFF_WUP);
  bfbits* wdn_t  = (bfbits*)(ws + OFF_WDN);
  float*  bvec   = (float*)(ws + OFF_BVEC);
  float*  cbv    = (float*)(ws + OFF_CBV);
  float*  gate   = (float*)(ws + OFF_GATE);
  float*  part   = (float*)(ws + OFF_PART);
  float*  pool   = (float*)(ws + OFF_POOL);
  float*  cmt    = (float*)(ws + OFF_CMT);

  float* outx   = (float*)d_out;
  float* outc   = outx + NELEM_X;          // center [B][DC]
  float* outg   = outc + B_ * DC_;         // gate [B][T]
  float* outcmt = outg + B_ * T_;          // commit [B]

  // weight prep (B^T bf16)
  transpose_w<<<dim3(32, 32), 256, 0, stream>>>(wq, wqkv_t,                1024, 1024, 1024, 1024);
  transpose_w<<<dim3(32, 32), 256, 0, stream>>>(wk, wqkv_t + 1024 * 1024,  1024, 1024, 1024, 1024);
  transpose_w<<<dim3(32, 32), 256, 0, stream>>>(wv, wqkv_t + 2048 * 1024,  1024, 1024, 1024, 1024);
  transpose_w<<<dim3(32, 32), 256, 0, stream>>>(wo, wo_t,                  1024, 1024, 1024, 1024);
  transpose_w<<<dim3(32, 52), 256, 0, stream>>>(up_w, wup_t,               1024, DFF_, 1024, DFFP_);
  transpose_w<<<dim3(52, 32), 256, 0, stream>>>(dn_w, wdn_t,               DFF_, 1024, DFFP_, 1024);

  gemv_t<<<dim3(32, B_), 256, 0, stream>>>(cfa, bcast_w, bcast_b, bvec, 0);
  cb_kernel<<<B_, 256, 0, stream>>>(cfa, cb_w, cbv);

  ln1_kernel<<<MTOT, 256, 0, stream>>>(x, bvec, cbv, gate_w, gate_b, nf_g, nf_b,
                                       x1, h, gate, outg);

  gemm_bt<0, 128><<<dim3(24, 32), 256, 0, stream>>>(
      h, 1024, wqkv_t, 1024, 1024, gate, phase, nullptr,
      nullptr, nullptr, qb, kb, vt);

  attn_kernel<<<1024, 128, 0, stream>>>(qb, kb, vt, ao);

  gemm_bt<1, 64><<<dim3(8, 64), 256, 0, stream>>>(
      ao, 1024, wo_t, 1024, 1024, gate, nullptr, nullptr,
      x2, x1, nullptr, nullptr, nullptr);

  ln2_kernel<<<MTOT, 256, 0, stream>>>(x2, nb_g, nb_b, h2);

  // pooled stats only need x2 -> run before FF so DN can fuse the final add
  pool_part<<<dim3(16, B_), 256, 0, stream>>>(x2, part);
  pool_fin<<<8, 256, 0, stream>>>(part, pool);
  commit_kernel<<<B_, 256, 0, stream>>>(pool, cmt_w, cmt_b, cmt, outcmt);
  gemv_t<<<dim3(32, B_), 256, 0, stream>>>(pool, cproj_w, cproj_b, outc, 1);

  gemm_bt<2, 64><<<dim3(13, 64), 256, 0, stream>>>(
      h2, 1024, wup_t, 1024, 1024, up_b, nullptr, nullptr,
      nullptr, nullptr, ffmid, nullptr, nullptr);

  gemm_bt<3, 64><<<dim3(8, 64), 256, 0, stream>>>(
      ffmid, DFFP_, wdn_t, DFFP_, DFFP_, dn_b, gate, cmt,
      outx, x2, nullptr, nullptr, nullptr);
}